// Round 5
// baseline (3398.120 us; speedup 1.0000x reference)
//
#include <hip/hip_runtime.h>
#include <hip/hip_bf16.h>
#include <cstdint>

#define F_IN 128
#define F_HID 64
#define NB 64          // nodes per bucket
#define MAXB 2048      // max buckets (N <= 131072)
#define NWG 256        // WGs for hist/fill edge partition

__device__ __forceinline__ float bf2f(unsigned short u) {
  return __uint_as_float(((unsigned int)u) << 16);
}
__device__ __forceinline__ unsigned short f2bf(float f) {
  unsigned int u = __float_as_uint(f);
  u += 0x7FFFu + ((u >> 16) & 1u);   // round-to-nearest-even
  return (unsigned short)(u >> 16);
}

// ---------------- dtype detection (resolved bf16 on this dataset) ----------------
__global__ __launch_bounds__(64) void k_detect(const unsigned int* __restrict__ Xw,
                                               int* __restrict__ flag) {
  int lane = threadIdx.x;
  int cnt = 0;
  for (int t = lane; t < 256; t += 64) {
    unsigned int ex = (Xw[t] >> 7) & 0xFFu;
    cnt += (ex >= 117u && ex <= 137u) ? 1 : 0;
  }
#pragma unroll
  for (int off = 32; off > 0; off >>= 1) cnt += __shfl_xor(cnt, off, 64);
  if (lane == 0) *flag = (cnt >= 128) ? 1 : 0;  // 1 = bf16, 0 = fp32
}

// ---------------- bucket build (no global atomics) ----------------
// hist layout: hist[b * NWG + w] = #edges of WG-w's chunk landing in bucket b
__global__ __launch_bounds__(256) void k_bhist(const int* __restrict__ dst,
                                               int* __restrict__ hist,
                                               int E, int B, int chunk) {
  __shared__ int lh[MAXB];
  int w = blockIdx.x, tid = threadIdx.x;
  for (int b = tid; b < B; b += 256) lh[b] = 0;
  __syncthreads();
  int e0 = w * chunk, e1 = min(E, e0 + chunk);
  for (int e = e0 + tid; e < e1; e += 256) atomicAdd(&lh[dst[e] >> 6], 1);
  __syncthreads();
  for (int b = tid; b < B; b += 256) hist[b * NWG + w] = lh[b];
}

// single WG: per-(bucket,WG) exclusive offsets in hist, bucket starts in boff
__global__ __launch_bounds__(256) void k_bscan(int* __restrict__ hist,
                                               int* __restrict__ boff,
                                               int B, int E) {
  __shared__ int partial[256];
  int t = threadIdx.x;
  int CH = (B + 255) / 256;
  int b0 = t * CH, b1 = min(B, b0 + CH);
  int tt = 0;
  for (int b = b0; b < b1; b++) {
    int acc = 0;
    for (int w = 0; w < NWG; w++) {
      int idx = b * NWG + w;
      int v = hist[idx];
      hist[idx] = acc;
      acc += v;
    }
    boff[b] = acc;  // temp: bucket total
    tt += acc;
  }
  partial[t] = tt;
  __syncthreads();
  if (t == 0) {
    int acc = 0;
    for (int i = 0; i < 256; i++) { int v = partial[i]; partial[i] = acc; acc += v; }
  }
  __syncthreads();
  int off = partial[t];
  for (int b = b0; b < b1; b++) { int v = boff[b]; boff[b] = off; off += v; }
  if (t == 0) boff[B] = E;
}

// fill: same edge partition as k_bhist; positions via LDS cursors only.
// record = (dst_local << 17) | src   (needs N <= 131072)
__global__ __launch_bounds__(256) void k_bfill(const int* __restrict__ src,
                                               const int* __restrict__ dst,
                                               const int* __restrict__ hist,
                                               const int* __restrict__ boff,
                                               int* __restrict__ buck,
                                               int E, int B, int chunk) {
  __shared__ int cur[MAXB];
  int w = blockIdx.x, tid = threadIdx.x;
  for (int b = tid; b < B; b += 256) cur[b] = boff[b] + hist[b * NWG + w];
  __syncthreads();
  int e0 = w * chunk, e1 = min(E, e0 + chunk);
  for (int e = e0 + tid; e < e1; e += 256) {
    int d = dst[e];
    int b = d >> 6, dl = d & 63;
    int p = atomicAdd(&cur[b], 1);
    buck[p] = (dl << 17) | src[e];
  }
}

// degrees -> dinv, from buckets (LDS counters, no global atomics)
__global__ __launch_bounds__(256) void k_bdeg(const int* __restrict__ buck,
                                              const int* __restrict__ boff,
                                              float* __restrict__ dinv, int N) {
  __shared__ int icnt[NB];
  int b = blockIdx.x, tid = threadIdx.x;
  if (tid < NB) icnt[tid] = 0;
  __syncthreads();
  int r0 = boff[b], r1 = boff[b + 1];
  for (int r = r0 + tid; r < r1; r += 256) atomicAdd(&icnt[buck[r] >> 17], 1);
  __syncthreads();
  if (tid < NB) {
    int n = b * NB + tid;
    if (n < N) dinv[n] = rsqrtf((float)icnt[tid] + 1.0f);  // +1 self-loop
  }
}

// ---------------- GEMM1: A = (X @ W1) * dinv[row] ----------------
template <bool ISB>
__device__ __forceinline__ void gemm1_body(const void* __restrict__ Xv,
                                           const float* __restrict__ sW,
                                           const float* __restrict__ dinv,
                                           float* __restrict__ A, int N,
                                           int lane, int wave) {
  const int RPW = 8;
  for (int r0 = (blockIdx.x * 4 + wave) * RPW; r0 < N; r0 += gridDim.x * 4 * RPW) {
    float acc[RPW];
#pragma unroll
    for (int r = 0; r < RPW; r++) acc[r] = 0.f;
    for (int k4 = 0; k4 < F_IN / 4; ++k4) {
      float w0 = sW[(k4 * 4 + 0) * F_HID + lane];
      float w1 = sW[(k4 * 4 + 1) * F_HID + lane];
      float w2 = sW[(k4 * 4 + 2) * F_HID + lane];
      float w3 = sW[(k4 * 4 + 3) * F_HID + lane];
#pragma unroll
      for (int r = 0; r < RPW; r++) {
        int rr = r0 + r; rr = rr < N ? rr : N - 1;
        float x0, x1, x2, x3;
        if (ISB) {
          ushort4 xv = *reinterpret_cast<const ushort4*>(
              (const unsigned short*)Xv + (size_t)rr * F_IN + k4 * 4);
          x0 = bf2f(xv.x); x1 = bf2f(xv.y); x2 = bf2f(xv.z); x3 = bf2f(xv.w);
        } else {
          float4 xv = *reinterpret_cast<const float4*>(
              (const float*)Xv + (size_t)rr * F_IN + k4 * 4);
          x0 = xv.x; x1 = xv.y; x2 = xv.z; x3 = xv.w;
        }
        acc[r] += x0 * w0 + x1 * w1 + x2 * w2 + x3 * w3;
      }
    }
#pragma unroll
    for (int r = 0; r < RPW; r++) {
      int rr = r0 + r;
      if (rr < N) A[(size_t)rr * F_HID + lane] = acc[r] * dinv[rr];
    }
  }
}

__global__ __launch_bounds__(256) void k_gemm1(const void* __restrict__ Xv,
                                               const void* __restrict__ Wv,
                                               const float* __restrict__ dinv,
                                               float* __restrict__ A, int N,
                                               const int* __restrict__ flagp) {
  __shared__ float sW[F_IN * F_HID];  // 32 KB
  const bool isb = (*flagp != 0);
  int tid = threadIdx.x;
  for (int t = tid; t < F_IN * F_HID; t += 256)
    sW[t] = isb ? bf2f(((const unsigned short*)Wv)[t]) : ((const float*)Wv)[t];
  __syncthreads();
  const int lane = tid & 63;
  const int wave = tid >> 6;
  if (isb) gemm1_body<true>(Xv, sW, dinv, A, N, lane, wave);
  else     gemm1_body<false>(Xv, sW, dinv, A, N, lane, wave);
}

// ---------------- GEMM2: Bout = (Xin @ W2) * dinv[row] ----------------
__global__ __launch_bounds__(256) void k_gemm2(const float* __restrict__ Xin,
                                               const void* __restrict__ Wv,
                                               const float* __restrict__ dinv,
                                               float* __restrict__ Bout, int N,
                                               const int* __restrict__ flagp) {
  __shared__ float sW[F_HID * F_HID];  // 16 KB
  const bool isb = (*flagp != 0);
  int tid = threadIdx.x;
  for (int t = tid; t < F_HID * F_HID; t += 256)
    sW[t] = isb ? bf2f(((const unsigned short*)Wv)[t]) : ((const float*)Wv)[t];
  __syncthreads();
  const int lane = tid & 63;
  const int wave = tid >> 6;
  const int RPW = 8;
  for (int r0 = (blockIdx.x * 4 + wave) * RPW; r0 < N; r0 += gridDim.x * 4 * RPW) {
    float acc[RPW];
#pragma unroll
    for (int r = 0; r < RPW; r++) acc[r] = 0.f;
    for (int k4 = 0; k4 < F_HID / 4; ++k4) {
      float w0 = sW[(k4 * 4 + 0) * F_HID + lane];
      float w1 = sW[(k4 * 4 + 1) * F_HID + lane];
      float w2 = sW[(k4 * 4 + 2) * F_HID + lane];
      float w3 = sW[(k4 * 4 + 3) * F_HID + lane];
#pragma unroll
      for (int r = 0; r < RPW; r++) {
        int rr = r0 + r; rr = rr < N ? rr : N - 1;
        float4 xv = *reinterpret_cast<const float4*>(Xin + (size_t)rr * F_HID + k4 * 4);
        acc[r] += xv.x * w0 + xv.y * w1 + xv.z * w2 + xv.w * w3;
      }
    }
#pragma unroll
    for (int r = 0; r < RPW; r++) {
      int rr = r0 + r;
      if (rr < N) Bout[(size_t)rr * F_HID + lane] = acc[r] * dinv[rr];
    }
  }
}

// ---------------- bucketed aggregate + fused epilogue ----------------
// One WG per bucket. LDS-accumulate 64 node rows (ds_add_f32, 2 lanes/bank =
// conflict-free), then OUT[n] = relu?((acc + H[n]) * dinv[n] + bias).
template <bool RELU>
__global__ __launch_bounds__(256) void k_bagg(const int* __restrict__ buck,
                                              const int* __restrict__ boff,
                                              const float* __restrict__ H,
                                              const float* __restrict__ dinv,
                                              const void* __restrict__ bias,
                                              float* __restrict__ OUT, int N,
                                              const int* __restrict__ flagp) {
  __shared__ float facc[NB * F_HID];  // 16 KB
  const bool isb = (*flagp != 0);
  int b = blockIdx.x, tid = threadIdx.x;
  int lane = tid & 63, wave = tid >> 6;
  for (int i = tid; i < NB * F_HID; i += 256) facc[i] = 0.f;
  __syncthreads();
  int r0 = boff[b], r1 = boff[b + 1];
  for (int base = r0 + wave * 64; base < r1; base += 4 * 64) {
    int cnt = min(64, r1 - base);
    int rec = (base + lane < r1) ? buck[base + lane] : 0;
    int k = 0;
    for (; k + 3 < cnt; k += 4) {
      int q0 = __shfl(rec, k, 64);
      int q1 = __shfl(rec, k + 1, 64);
      int q2 = __shfl(rec, k + 2, 64);
      int q3 = __shfl(rec, k + 3, 64);
      float v0 = H[(size_t)(q0 & 0x1FFFF) * F_HID + lane];
      float v1 = H[(size_t)(q1 & 0x1FFFF) * F_HID + lane];
      float v2 = H[(size_t)(q2 & 0x1FFFF) * F_HID + lane];
      float v3 = H[(size_t)(q3 & 0x1FFFF) * F_HID + lane];
      atomicAdd(&facc[((q0 >> 17) << 6) + lane], v0);
      atomicAdd(&facc[((q1 >> 17) << 6) + lane], v1);
      atomicAdd(&facc[((q2 >> 17) << 6) + lane], v2);
      atomicAdd(&facc[((q3 >> 17) << 6) + lane], v3);
    }
    for (; k < cnt; k++) {
      int q0 = __shfl(rec, k, 64);
      atomicAdd(&facc[((q0 >> 17) << 6) + lane],
                H[(size_t)(q0 & 0x1FFFF) * F_HID + lane]);
    }
  }
  __syncthreads();
  float bv = isb ? bf2f(((const unsigned short*)bias)[lane])
                 : ((const float*)bias)[lane];
  for (int dl = wave; dl < NB; dl += 4) {
    int n = b * NB + dl;
    if (n >= N) break;
    float g = facc[(dl << 6) + lane];
    float a = H[(size_t)n * F_HID + lane];  // self term (already * dinv[n])
    float o = (g + a) * dinv[n] + bv;
    if (RELU) o = fmaxf(o, 0.f);
    OUT[(size_t)n * F_HID + lane] = o;
  }
}

// ---------------- PR GEMM: PR[n][0:128] = out2[n] @ Wa ; PR[n][128:256] = out2[n] @ Wb ----------------
__global__ __launch_bounds__(256) void k_gemm_pr(const float* __restrict__ Xin,
                                                 const void* __restrict__ fc1Wv,
                                                 float* __restrict__ PR, int N,
                                                 const int* __restrict__ flagp) {
  __shared__ unsigned short sW[F_HID * 256];  // 32 KB bf16
  const bool isb = (*flagp != 0);
  int tid = threadIdx.x;
  for (int t = tid; t < F_HID * 256; t += 256) {
    int k = t >> 8, h = t & 255;
    int idx = (h < 128) ? (k * 128 + h) : ((64 + k) * 128 + (h - 128));
    sW[t] = isb ? ((const unsigned short*)fc1Wv)[idx]
                : f2bf(((const float*)fc1Wv)[idx]);
  }
  __syncthreads();
  const int lane = tid & 63;
  const int wave = tid >> 6;
  const int RPW = 8;
  for (int r0 = (blockIdx.x * 4 + wave) * RPW; r0 < N; r0 += gridDim.x * 4 * RPW) {
    float acc[RPW][4];
#pragma unroll
    for (int r = 0; r < RPW; r++)
#pragma unroll
      for (int c = 0; c < 4; c++) acc[r][c] = 0.f;
    for (int k4 = 0; k4 < F_HID / 4; ++k4) {
      float w[4][4];
#pragma unroll
      for (int kk = 0; kk < 4; kk++)
#pragma unroll
        for (int c = 0; c < 4; c++)
          w[kk][c] = bf2f(sW[(k4 * 4 + kk) * 256 + c * 64 + lane]);
#pragma unroll
      for (int r = 0; r < RPW; r++) {
        int rr = r0 + r; rr = rr < N ? rr : N - 1;
        float4 xv = *reinterpret_cast<const float4*>(Xin + (size_t)rr * F_HID + k4 * 4);
#pragma unroll
        for (int c = 0; c < 4; c++)
          acc[r][c] += xv.x * w[0][c] + xv.y * w[1][c] + xv.z * w[2][c] + xv.w * w[3][c];
      }
    }
#pragma unroll
    for (int r = 0; r < RPW; r++) {
      int rr = r0 + r;
      if (rr < N) {
#pragma unroll
        for (int c = 0; c < 4; c++)
          PR[(size_t)rr * 256 + c * 64 + lane] = acc[r][c];
      }
    }
  }
}

// ---------------- query: out[q] = relu(P[i[q]] + R[j[q]] + fc1_b) @ fc2_W + fc2_b ----------------
__global__ __launch_bounds__(256) void k_query(const float* __restrict__ PR,
                                               const int* __restrict__ qi,
                                               const int* __restrict__ qj,
                                               const void* __restrict__ fc1b,
                                               const void* __restrict__ fc2W,
                                               const void* __restrict__ fc2b,
                                               void* __restrict__ out, int Q,
                                               const int* __restrict__ flagp) {
  const bool isb = (*flagp != 0);
  int tid = threadIdx.x;
  int lane = tid & 63;
  int wave = tid >> 6;
  int g = lane >> 4, m = lane & 15;
  float bb[8], w0[8], w1[8];
#pragma unroll
  for (int t = 0; t < 8; t++) {
    int h = m * 8 + t;
    if (isb) {
      bb[t] = bf2f(((const unsigned short*)fc1b)[h]);
      w0[t] = bf2f(((const unsigned short*)fc2W)[h * 2 + 0]);
      w1[t] = bf2f(((const unsigned short*)fc2W)[h * 2 + 1]);
    } else {
      bb[t] = ((const float*)fc1b)[h];
      w0[t] = ((const float*)fc2W)[h * 2 + 0];
      w1[t] = ((const float*)fc2W)[h * 2 + 1];
    }
  }
  float ob0 = isb ? bf2f(((const unsigned short*)fc2b)[0]) : ((const float*)fc2b)[0];
  float ob1 = isb ? bf2f(((const unsigned short*)fc2b)[1]) : ((const float*)fc2b)[1];
  int gw = blockIdx.x * 4 + wave;
  int nW = gridDim.x * 4;
  int nQuad = (Q + 3) >> 2;
  for (int quad = gw; quad < nQuad; quad += nW) {
    int q = quad * 4 + g;
    int qq = q < Q ? q : Q - 1;
    int iq = qi[qq], jq = qj[qq];
    const float4* Pr = reinterpret_cast<const float4*>(PR + (size_t)iq * 256);
    const float4* Rr = reinterpret_cast<const float4*>(PR + (size_t)jq * 256 + 128);
    float4 pa = Pr[m * 2], pb = Pr[m * 2 + 1];
    float4 ra = Rr[m * 2], rb = Rr[m * 2 + 1];
    float h[8] = {pa.x + ra.x, pa.y + ra.y, pa.z + ra.z, pa.w + ra.w,
                  pb.x + rb.x, pb.y + rb.y, pb.z + rb.z, pb.w + rb.w};
    float r0 = 0.f, r1 = 0.f;
#pragma unroll
    for (int t = 0; t < 8; t++) {
      float hv = fmaxf(h[t] + bb[t], 0.f);
      r0 += hv * w0[t];
      r1 += hv * w1[t];
    }
#pragma unroll
    for (int off = 8; off > 0; off >>= 1) {
      r0 += __shfl_xor(r0, off, 16);
      r1 += __shfl_xor(r1, off, 16);
    }
    if (m == 0 && q < Q) {
      if (isb) {
        *reinterpret_cast<ushort2*>((unsigned short*)out + (size_t)q * 2) =
            make_ushort2(f2bf(r0 + ob0), f2bf(r1 + ob1));
      } else {
        *reinterpret_cast<float2*>((float*)out + (size_t)q * 2) =
            make_float2(r0 + ob0, r1 + ob1);
      }
    }
  }
}

extern "C" void kernel_launch(void* const* d_in, const int* in_sizes, int n_in,
                              void* d_out, int out_size, void* d_ws, size_t ws_size,
                              hipStream_t stream) {
  const void* X    = d_in[0];
  const int*  edges= (const int*)d_in[1];
  const int*  qi   = (const int*)d_in[2];
  const int*  qj   = (const int*)d_in[3];
  const void* W1   = d_in[4];
  const void* b1   = d_in[5];
  const void* W2   = d_in[6];
  const void* b2   = d_in[7];
  const void* fc1W = d_in[8];
  const void* fc1b = d_in[9];
  const void* fc2W = d_in[10];
  const void* fc2b = d_in[11];

  const int N = in_sizes[0] / F_IN;
  const int E = in_sizes[1] / 2;
  const int Q = in_sizes[2];
  const int B = (N + NB - 1) / NB;           // buckets (<= MAXB for N <= 131072)
  const int chunk = (E + NWG - 1) / NWG;

  char* ws = (char*)d_ws;
  size_t off = 0;
  auto alloc = [&](size_t bytes) -> void* {
    void* p = ws + off;
    off += (bytes + 255) & ~(size_t)255;
    return p;
  };
  int*   flag = (int*)alloc(4);
  float* dinv = (float*)alloc((size_t)N * 4);
  float* A    = (float*)alloc((size_t)N * F_HID * 4);   // G1 -> G2
  float* Bf   = (float*)alloc((size_t)N * F_HID * 4);   // O1 -> O2
  float* PR   = (float*)alloc((size_t)N * 256 * 4);     // [P | R]
  // bucket scratch aliases PR (all bucket reads precede gemm_pr's PR writes)
  int* hist = (int*)PR;                 // B * NWG
  int* boff = hist + (size_t)B * NWG;   // B + 1
  int* buck = boff + B + 256;           // E
  (void)ws_size; (void)n_in; (void)out_size;

  const int* esrc = edges;
  const int* edst = edges + E;

  k_detect<<<1, 64, 0, stream>>>((const unsigned int*)X, flag);

  // bucket build (shared by both layers) + degrees
  k_bhist<<<NWG, 256, 0, stream>>>(edst, hist, E, B, chunk);
  k_bscan<<<1, 256, 0, stream>>>(hist, boff, B, E);
  k_bfill<<<NWG, 256, 0, stream>>>(esrc, edst, hist, boff, buck, E, B, chunk);
  k_bdeg<<<B, 256, 0, stream>>>(buck, boff, dinv, N);

  // layer 1
  k_gemm1<<<1024, 256, 0, stream>>>(X, W1, dinv, A, N, flag);
  k_bagg<true><<<B, 256, 0, stream>>>(buck, boff, A, dinv, b1, Bf, N, flag);

  // layer 2
  k_gemm2<<<1024, 256, 0, stream>>>(Bf, W2, dinv, A, N, flag);
  k_bagg<false><<<B, 256, 0, stream>>>(buck, boff, A, dinv, b2, Bf, N, flag);

  // MLP factorization: PR = out2 @ [Wa | Wb]  (overwrites bucket scratch — safe)
  k_gemm_pr<<<1024, 256, 0, stream>>>(Bf, fc1W, PR, N, flag);

  // per-query: gather P[i] + R[j], relu, fc2
  k_query<<<4096, 256, 0, stream>>>(PR, qi, qj, fc1b, fc2W, fc2b, d_out, Q, flag);
}

// Round 6
// 1192.809 us; speedup vs baseline: 2.8488x; 2.8488x over previous
//
#include <hip/hip_runtime.h>
#include <hip/hip_bf16.h>
#include <cstdint>

#define F_IN 128
#define F_HID 64
#define NB 64          // nodes per bucket
#define MAXB 2048      // max buckets (N <= 131072)
#define NWG 256        // WGs for hist/fill edge partition

__device__ __forceinline__ float bf2f(unsigned short u) {
  return __uint_as_float(((unsigned int)u) << 16);
}
__device__ __forceinline__ unsigned short f2bf(float f) {
  unsigned int u = __float_as_uint(f);
  u += 0x7FFFu + ((u >> 16) & 1u);   // round-to-nearest-even
  return (unsigned short)(u >> 16);
}

// ---------------- dtype detection (resolved bf16 on this dataset) ----------------
__global__ __launch_bounds__(64) void k_detect(const unsigned int* __restrict__ Xw,
                                               int* __restrict__ flag) {
  int lane = threadIdx.x;
  int cnt = 0;
  for (int t = lane; t < 256; t += 64) {
    unsigned int ex = (Xw[t] >> 7) & 0xFFu;
    cnt += (ex >= 117u && ex <= 137u) ? 1 : 0;
  }
#pragma unroll
  for (int off = 32; off > 0; off >>= 1) cnt += __shfl_xor(cnt, off, 64);
  if (lane == 0) *flag = (cnt >= 128) ? 1 : 0;  // 1 = bf16, 0 = fp32
}

// ---------------- bucket build (no global atomics) ----------------
// hist layout: hist[b * NWG + w] = #edges of WG-w's chunk landing in bucket b
__global__ __launch_bounds__(256) void k_bhist(const int* __restrict__ dst,
                                               int* __restrict__ hist,
                                               int E, int B, int chunk) {
  __shared__ int lh[MAXB];
  int w = blockIdx.x, tid = threadIdx.x;
  for (int b = tid; b < B; b += 256) lh[b] = 0;
  __syncthreads();
  int e0 = w * chunk, e1 = min(E, e0 + chunk);
  for (int e = e0 + tid; e < e1; e += 256) atomicAdd(&lh[dst[e] >> 6], 1);
  __syncthreads();
  for (int b = tid; b < B; b += 256) hist[b * NWG + w] = lh[b];
}

// single WG: per-(bucket,WG) exclusive offsets in hist, bucket starts in boff
__global__ __launch_bounds__(256) void k_bscan(int* __restrict__ hist,
                                               int* __restrict__ boff,
                                               int B, int E) {
  __shared__ int partial[256];
  int t = threadIdx.x;
  int CH = (B + 255) / 256;
  int b0 = t * CH, b1 = min(B, b0 + CH);
  int tt = 0;
  for (int b = b0; b < b1; b++) {
    int acc = 0;
    for (int w = 0; w < NWG; w++) {
      int idx = b * NWG + w;
      int v = hist[idx];
      hist[idx] = acc;
      acc += v;
    }
    boff[b] = acc;  // temp: bucket total
    tt += acc;
  }
  partial[t] = tt;
  __syncthreads();
  if (t == 0) {
    int acc = 0;
    for (int i = 0; i < 256; i++) { int v = partial[i]; partial[i] = acc; acc += v; }
  }
  __syncthreads();
  int off = partial[t];
  for (int b = b0; b < b1; b++) { int v = boff[b]; boff[b] = off; off += v; }
  if (t == 0) boff[B] = E;
}

// fill: same edge partition as k_bhist; positions via LDS cursors only.
// record = (dst_local << 17) | src   (needs N <= 131072)
__global__ __launch_bounds__(256) void k_bfill(const int* __restrict__ src,
                                               const int* __restrict__ dst,
                                               const int* __restrict__ hist,
                                               const int* __restrict__ boff,
                                               int* __restrict__ buck,
                                               int E, int B, int chunk) {
  __shared__ int cur[MAXB];
  int w = blockIdx.x, tid = threadIdx.x;
  for (int b = tid; b < B; b += 256) cur[b] = boff[b] + hist[b * NWG + w];
  __syncthreads();
  int e0 = w * chunk, e1 = min(E, e0 + chunk);
  for (int e = e0 + tid; e < e1; e += 256) {
    int d = dst[e];
    int b = d >> 6, dl = d & 63;
    int p = atomicAdd(&cur[b], 1);
    buck[p] = (dl << 17) | src[e];
  }
}

// ---------------- per-bucket counting sort -> exact per-node CSR ----------------
// One WG per bucket. 64 bins (int LDS atomics = native HW). Emits:
//   csr[r0..r1): src indices grouped by destination node
//   noff[n]: global start of node n's segment (noff[N] = E, monotone)
//   dinv[n]
__global__ __launch_bounds__(256) void k_bsort(const int* __restrict__ buck,
                                               const int* __restrict__ boff,
                                               int* __restrict__ csr,
                                               int* __restrict__ noff,
                                               float* __restrict__ dinv, int N) {
  __shared__ int bin[NB];
  __shared__ int excl[NB];
  int b = blockIdx.x, tid = threadIdx.x;
  if (tid < NB) bin[tid] = 0;
  __syncthreads();
  int r0 = boff[b], r1 = boff[b + 1];
  for (int r = r0 + tid; r < r1; r += 256) atomicAdd(&bin[buck[r] >> 17], 1);
  __syncthreads();
  if (tid == 0) {
    int acc = 0;
    for (int i = 0; i < NB; i++) { excl[i] = acc; acc += bin[i]; }
  }
  __syncthreads();
  if (tid < NB) {
    int n = b * NB + tid;
    if (n < N) {
      dinv[n] = rsqrtf((float)bin[tid] + 1.0f);  // +1 self-loop
      noff[n] = r0 + excl[tid];
    }
  }
  if (b == gridDim.x - 1 && tid == 128) noff[N] = r1;  // r1 == E for last bucket
  __syncthreads();
  if (tid < NB) bin[tid] = excl[tid];  // reuse as cursors
  __syncthreads();
  for (int r = r0 + tid; r < r1; r += 256) {
    int rec = buck[r];
    int p = atomicAdd(&bin[rec >> 17], 1);
    csr[r0 + p] = rec & 0x1FFFF;
  }
}

// ---------------- GEMM1: A = (X @ W1) * dinv[row] ----------------
template <bool ISB>
__device__ __forceinline__ void gemm1_body(const void* __restrict__ Xv,
                                           const float* __restrict__ sW,
                                           const float* __restrict__ dinv,
                                           float* __restrict__ A, int N,
                                           int lane, int wave) {
  const int RPW = 8;
  for (int r0 = (blockIdx.x * 4 + wave) * RPW; r0 < N; r0 += gridDim.x * 4 * RPW) {
    float acc[RPW];
#pragma unroll
    for (int r = 0; r < RPW; r++) acc[r] = 0.f;
    for (int k4 = 0; k4 < F_IN / 4; ++k4) {
      float w0 = sW[(k4 * 4 + 0) * F_HID + lane];
      float w1 = sW[(k4 * 4 + 1) * F_HID + lane];
      float w2 = sW[(k4 * 4 + 2) * F_HID + lane];
      float w3 = sW[(k4 * 4 + 3) * F_HID + lane];
#pragma unroll
      for (int r = 0; r < RPW; r++) {
        int rr = r0 + r; rr = rr < N ? rr : N - 1;
        float x0, x1, x2, x3;
        if (ISB) {
          ushort4 xv = *reinterpret_cast<const ushort4*>(
              (const unsigned short*)Xv + (size_t)rr * F_IN + k4 * 4);
          x0 = bf2f(xv.x); x1 = bf2f(xv.y); x2 = bf2f(xv.z); x3 = bf2f(xv.w);
        } else {
          float4 xv = *reinterpret_cast<const float4*>(
              (const float*)Xv + (size_t)rr * F_IN + k4 * 4);
          x0 = xv.x; x1 = xv.y; x2 = xv.z; x3 = xv.w;
        }
        acc[r] += x0 * w0 + x1 * w1 + x2 * w2 + x3 * w3;
      }
    }
#pragma unroll
    for (int r = 0; r < RPW; r++) {
      int rr = r0 + r;
      if (rr < N) A[(size_t)rr * F_HID + lane] = acc[r] * dinv[rr];
    }
  }
}

__global__ __launch_bounds__(256) void k_gemm1(const void* __restrict__ Xv,
                                               const void* __restrict__ Wv,
                                               const float* __restrict__ dinv,
                                               float* __restrict__ A, int N,
                                               const int* __restrict__ flagp) {
  __shared__ float sW[F_IN * F_HID];  // 32 KB
  const bool isb = (*flagp != 0);
  int tid = threadIdx.x;
  for (int t = tid; t < F_IN * F_HID; t += 256)
    sW[t] = isb ? bf2f(((const unsigned short*)Wv)[t]) : ((const float*)Wv)[t];
  __syncthreads();
  const int lane = tid & 63;
  const int wave = tid >> 6;
  if (isb) gemm1_body<true>(Xv, sW, dinv, A, N, lane, wave);
  else     gemm1_body<false>(Xv, sW, dinv, A, N, lane, wave);
}

// ---------------- GEMM2: Bout = (Xin @ W2) * dinv[row] ----------------
__global__ __launch_bounds__(256) void k_gemm2(const float* __restrict__ Xin,
                                               const void* __restrict__ Wv,
                                               const float* __restrict__ dinv,
                                               float* __restrict__ Bout, int N,
                                               const int* __restrict__ flagp) {
  __shared__ float sW[F_HID * F_HID];  // 16 KB
  const bool isb = (*flagp != 0);
  int tid = threadIdx.x;
  for (int t = tid; t < F_HID * F_HID; t += 256)
    sW[t] = isb ? bf2f(((const unsigned short*)Wv)[t]) : ((const float*)Wv)[t];
  __syncthreads();
  const int lane = tid & 63;
  const int wave = tid >> 6;
  const int RPW = 8;
  for (int r0 = (blockIdx.x * 4 + wave) * RPW; r0 < N; r0 += gridDim.x * 4 * RPW) {
    float acc[RPW];
#pragma unroll
    for (int r = 0; r < RPW; r++) acc[r] = 0.f;
    for (int k4 = 0; k4 < F_HID / 4; ++k4) {
      float w0 = sW[(k4 * 4 + 0) * F_HID + lane];
      float w1 = sW[(k4 * 4 + 1) * F_HID + lane];
      float w2 = sW[(k4 * 4 + 2) * F_HID + lane];
      float w3 = sW[(k4 * 4 + 3) * F_HID + lane];
#pragma unroll
      for (int r = 0; r < RPW; r++) {
        int rr = r0 + r; rr = rr < N ? rr : N - 1;
        float4 xv = *reinterpret_cast<const float4*>(Xin + (size_t)rr * F_HID + k4 * 4);
        acc[r] += xv.x * w0 + xv.y * w1 + xv.z * w2 + xv.w * w3;
      }
    }
#pragma unroll
    for (int r = 0; r < RPW; r++) {
      int rr = r0 + r;
      if (rr < N) Bout[(size_t)rr * F_HID + lane] = acc[r] * dinv[rr];
    }
  }
}

// ---------------- aggregate (exact CSR, REGISTER accumulation) + fused epilogue ----------------
// Wave per node. OUT[n] = relu?((sum_edges H[src] + H[n]) * dinv[n] + bias)
template <bool RELU>
__global__ __launch_bounds__(256) void k_agg(const int* __restrict__ csr,
                                             const int* __restrict__ noff,
                                             const float* __restrict__ H,
                                             const float* __restrict__ dinv,
                                             const void* __restrict__ bias,
                                             float* __restrict__ OUT, int N,
                                             const int* __restrict__ flagp) {
  const bool isb = (*flagp != 0);
  int lane = threadIdx.x & 63;
  int gw = (blockIdx.x * 256 + threadIdx.x) >> 6;
  int nW = (gridDim.x * 256) >> 6;
  float bv = isb ? bf2f(((const unsigned short*)bias)[lane])
                 : ((const float*)bias)[lane];
  for (int n = gw; n < N; n += nW) {
    int start = noff[n], end = noff[n + 1];
    float acc0 = 0.f, acc1 = 0.f;
    for (int e0 = start; e0 < end; e0 += 64) {
      int ee = e0 + lane;
      int idx = (ee < end) ? csr[ee] : 0;
      int m = end - e0; m = m < 64 ? m : 64;
      int k = 0;
      for (; k + 3 < m; k += 4) {
        int s0 = __shfl(idx, k, 64);
        int s1 = __shfl(idx, k + 1, 64);
        int s2 = __shfl(idx, k + 2, 64);
        int s3 = __shfl(idx, k + 3, 64);
        float v0 = H[(size_t)s0 * F_HID + lane];
        float v1 = H[(size_t)s1 * F_HID + lane];
        float v2 = H[(size_t)s2 * F_HID + lane];
        float v3 = H[(size_t)s3 * F_HID + lane];
        acc0 += v0 + v2;
        acc1 += v1 + v3;
      }
      for (; k < m; k++) {
        int s0 = __shfl(idx, k, 64);
        acc0 += H[(size_t)s0 * F_HID + lane];
      }
    }
    float self = H[(size_t)n * F_HID + lane];  // self-loop (already * dinv[n])
    float o = (acc0 + acc1 + self) * dinv[n] + bv;
    if (RELU) o = fmaxf(o, 0.f);
    OUT[(size_t)n * F_HID + lane] = o;
  }
}

// ---------------- PR GEMM: PR[n][0:128] = out2[n] @ Wa ; PR[n][128:256] = out2[n] @ Wb ----------------
__global__ __launch_bounds__(256) void k_gemm_pr(const float* __restrict__ Xin,
                                                 const void* __restrict__ fc1Wv,
                                                 float* __restrict__ PR, int N,
                                                 const int* __restrict__ flagp) {
  __shared__ unsigned short sW[F_HID * 256];  // 32 KB bf16
  const bool isb = (*flagp != 0);
  int tid = threadIdx.x;
  for (int t = tid; t < F_HID * 256; t += 256) {
    int k = t >> 8, h = t & 255;
    int idx = (h < 128) ? (k * 128 + h) : ((64 + k) * 128 + (h - 128));
    sW[t] = isb ? ((const unsigned short*)fc1Wv)[idx]
                : f2bf(((const float*)fc1Wv)[idx]);
  }
  __syncthreads();
  const int lane = tid & 63;
  const int wave = tid >> 6;
  const int RPW = 8;
  for (int r0 = (blockIdx.x * 4 + wave) * RPW; r0 < N; r0 += gridDim.x * 4 * RPW) {
    float acc[RPW][4];
#pragma unroll
    for (int r = 0; r < RPW; r++)
#pragma unroll
      for (int c = 0; c < 4; c++) acc[r][c] = 0.f;
    for (int k4 = 0; k4 < F_HID / 4; ++k4) {
      float w[4][4];
#pragma unroll
      for (int kk = 0; kk < 4; kk++)
#pragma unroll
        for (int c = 0; c < 4; c++)
          w[kk][c] = bf2f(sW[(k4 * 4 + kk) * 256 + c * 64 + lane]);
#pragma unroll
      for (int r = 0; r < RPW; r++) {
        int rr = r0 + r; rr = rr < N ? rr : N - 1;
        float4 xv = *reinterpret_cast<const float4*>(Xin + (size_t)rr * F_HID + k4 * 4);
#pragma unroll
        for (int c = 0; c < 4; c++)
          acc[r][c] += xv.x * w[0][c] + xv.y * w[1][c] + xv.z * w[2][c] + xv.w * w[3][c];
      }
    }
#pragma unroll
    for (int r = 0; r < RPW; r++) {
      int rr = r0 + r;
      if (rr < N) {
#pragma unroll
        for (int c = 0; c < 4; c++)
          PR[(size_t)rr * 256 + c * 64 + lane] = acc[r][c];
      }
    }
  }
}

// ---------------- query: out[q] = relu(P[i[q]] + R[j[q]] + fc1_b) @ fc2_W + fc2_b ----------------
__global__ __launch_bounds__(256) void k_query(const float* __restrict__ PR,
                                               const int* __restrict__ qi,
                                               const int* __restrict__ qj,
                                               const void* __restrict__ fc1b,
                                               const void* __restrict__ fc2W,
                                               const void* __restrict__ fc2b,
                                               void* __restrict__ out, int Q,
                                               const int* __restrict__ flagp) {
  const bool isb = (*flagp != 0);
  int tid = threadIdx.x;
  int lane = tid & 63;
  int wave = tid >> 6;
  int g = lane >> 4, m = lane & 15;
  float bb[8], w0[8], w1[8];
#pragma unroll
  for (int t = 0; t < 8; t++) {
    int h = m * 8 + t;
    if (isb) {
      bb[t] = bf2f(((const unsigned short*)fc1b)[h]);
      w0[t] = bf2f(((const unsigned short*)fc2W)[h * 2 + 0]);
      w1[t] = bf2f(((const unsigned short*)fc2W)[h * 2 + 1]);
    } else {
      bb[t] = ((const float*)fc1b)[h];
      w0[t] = ((const float*)fc2W)[h * 2 + 0];
      w1[t] = ((const float*)fc2W)[h * 2 + 1];
    }
  }
  float ob0 = isb ? bf2f(((const unsigned short*)fc2b)[0]) : ((const float*)fc2b)[0];
  float ob1 = isb ? bf2f(((const unsigned short*)fc2b)[1]) : ((const float*)fc2b)[1];
  int gw = blockIdx.x * 4 + wave;
  int nW = gridDim.x * 4;
  int nQuad = (Q + 3) >> 2;
  for (int quad = gw; quad < nQuad; quad += nW) {
    int q = quad * 4 + g;
    int qq = q < Q ? q : Q - 1;
    int iq = qi[qq], jq = qj[qq];
    const float4* Pr = reinterpret_cast<const float4*>(PR + (size_t)iq * 256);
    const float4* Rr = reinterpret_cast<const float4*>(PR + (size_t)jq * 256 + 128);
    float4 pa = Pr[m * 2], pb = Pr[m * 2 + 1];
    float4 ra = Rr[m * 2], rb = Rr[m * 2 + 1];
    float h[8] = {pa.x + ra.x, pa.y + ra.y, pa.z + ra.z, pa.w + ra.w,
                  pb.x + rb.x, pb.y + rb.y, pb.z + rb.z, pb.w + rb.w};
    float r0 = 0.f, r1 = 0.f;
#pragma unroll
    for (int t = 0; t < 8; t++) {
      float hv = fmaxf(h[t] + bb[t], 0.f);
      r0 += hv * w0[t];
      r1 += hv * w1[t];
    }
#pragma unroll
    for (int off = 8; off > 0; off >>= 1) {
      r0 += __shfl_xor(r0, off, 16);
      r1 += __shfl_xor(r1, off, 16);
    }
    if (m == 0 && q < Q) {
      if (isb) {
        *reinterpret_cast<ushort2*>((unsigned short*)out + (size_t)q * 2) =
            make_ushort2(f2bf(r0 + ob0), f2bf(r1 + ob1));
      } else {
        *reinterpret_cast<float2*>((float*)out + (size_t)q * 2) =
            make_float2(r0 + ob0, r1 + ob1);
      }
    }
  }
}

extern "C" void kernel_launch(void* const* d_in, const int* in_sizes, int n_in,
                              void* d_out, int out_size, void* d_ws, size_t ws_size,
                              hipStream_t stream) {
  const void* X    = d_in[0];
  const int*  edges= (const int*)d_in[1];
  const int*  qi   = (const int*)d_in[2];
  const int*  qj   = (const int*)d_in[3];
  const void* W1   = d_in[4];
  const void* b1   = d_in[5];
  const void* W2   = d_in[6];
  const void* b2   = d_in[7];
  const void* fc1W = d_in[8];
  const void* fc1b = d_in[9];
  const void* fc2W = d_in[10];
  const void* fc2b = d_in[11];

  const int N = in_sizes[0] / F_IN;
  const int E = in_sizes[1] / 2;
  const int Q = in_sizes[2];
  const int B = (N + NB - 1) / NB;           // buckets (<= MAXB for N <= 131072)
  const int chunk = (E + NWG - 1) / NWG;

  char* ws = (char*)d_ws;
  size_t off = 0;
  auto alloc = [&](size_t bytes) -> void* {
    void* p = ws + off;
    off += (bytes + 255) & ~(size_t)255;
    return p;
  };
  int*   flag = (int*)alloc(4);
  float* dinv = (float*)alloc((size_t)N * 4);
  float* A    = (float*)alloc((size_t)N * F_HID * 4);   // G1 -> G2
  float* Bf   = (float*)alloc((size_t)N * F_HID * 4);   // O1 -> O2
  float* PR   = (float*)alloc((size_t)N * 256 * 4);     // [P | R]
  // bucket/CSR scratch aliases PR (all reads precede gemm_pr's PR writes)
  char* scr = (char*)PR;
  size_t soff = 0;
  auto salloc = [&](size_t bytes) -> void* {
    void* p = scr + soff;
    soff += (bytes + 255) & ~(size_t)255;
    return p;
  };
  int* hist = (int*)salloc((size_t)B * NWG * 4);
  int* boff = (int*)salloc((size_t)(B + 1) * 4);
  int* buck = (int*)salloc((size_t)E * 4);
  int* csr  = (int*)salloc((size_t)E * 4);
  int* noff = (int*)salloc((size_t)(N + 1) * 4);
  (void)ws_size; (void)n_in; (void)out_size;

  const int* esrc = edges;
  const int* edst = edges + E;

  k_detect<<<1, 64, 0, stream>>>((const unsigned int*)X, flag);

  // bucket build + per-bucket counting sort -> exact CSR + noff + dinv
  k_bhist<<<NWG, 256, 0, stream>>>(edst, hist, E, B, chunk);
  k_bscan<<<1, 256, 0, stream>>>(hist, boff, B, E);
  k_bfill<<<NWG, 256, 0, stream>>>(esrc, edst, hist, boff, buck, E, B, chunk);
  k_bsort<<<B, 256, 0, stream>>>(buck, boff, csr, noff, dinv, N);

  // layer 1
  k_gemm1<<<1024, 256, 0, stream>>>(X, W1, dinv, A, N, flag);
  k_agg<true><<<2048, 256, 0, stream>>>(csr, noff, A, dinv, b1, Bf, N, flag);

  // layer 2
  k_gemm2<<<1024, 256, 0, stream>>>(Bf, W2, dinv, A, N, flag);
  k_agg<false><<<2048, 256, 0, stream>>>(csr, noff, A, dinv, b2, Bf, N, flag);

  // MLP factorization: PR = out2 @ [Wa | Wb]  (overwrites bucket scratch — safe)
  k_gemm_pr<<<1024, 256, 0, stream>>>(Bf, fc1W, PR, N, flag);

  // per-query: gather P[i] + R[j], relu, fc2
  k_query<<<4096, 256, 0, stream>>>(PR, qi, qj, fc1b, fc2W, fc2b, d_out, Q, flag);
}

// Round 7
// 1040.602 us; speedup vs baseline: 3.2655x; 1.1463x over previous
//
#include <hip/hip_runtime.h>
#include <hip/hip_bf16.h>
#include <cstdint>

#define F_IN 128
#define F_HID 64
#define NB 64          // nodes per bucket
#define MAXB 2048      // max buckets (N <= 131072)
#define NWG 256        // WGs for hist/fill edge partition

__device__ __forceinline__ float bf2f(unsigned short u) {
  return __uint_as_float(((unsigned int)u) << 16);
}
__device__ __forceinline__ unsigned short f2bf(float f) {
  unsigned int u = __float_as_uint(f);
  u += 0x7FFFu + ((u >> 16) & 1u);   // round-to-nearest-even
  return (unsigned short)(u >> 16);
}

// ---------------- dtype detection (resolved bf16 on this dataset) ----------------
__global__ __launch_bounds__(64) void k_detect(const unsigned int* __restrict__ Xw,
                                               int* __restrict__ flag) {
  int lane = threadIdx.x;
  int cnt = 0;
  for (int t = lane; t < 256; t += 64) {
    unsigned int ex = (Xw[t] >> 7) & 0xFFu;
    cnt += (ex >= 117u && ex <= 137u) ? 1 : 0;
  }
#pragma unroll
  for (int off = 32; off > 0; off >>= 1) cnt += __shfl_xor(cnt, off, 64);
  if (lane == 0) *flag = (cnt >= 128) ? 1 : 0;  // 1 = bf16, 0 = fp32
}

// ---------------- bucket build (no global atomics) ----------------
__global__ __launch_bounds__(256) void k_bhist(const int* __restrict__ dst,
                                               int* __restrict__ hist,
                                               int E, int B, int chunk) {
  __shared__ int lh[MAXB];
  int w = blockIdx.x, tid = threadIdx.x;
  for (int b = tid; b < B; b += 256) lh[b] = 0;
  __syncthreads();
  int e0 = w * chunk, e1 = min(E, e0 + chunk);
  for (int e = e0 + tid; e < e1; e += 256) atomicAdd(&lh[dst[e] >> 6], 1);
  __syncthreads();
  for (int b = tid; b < B; b += 256) hist[b * NWG + w] = lh[b];
}

__global__ __launch_bounds__(256) void k_bscan(int* __restrict__ hist,
                                               int* __restrict__ boff,
                                               int B, int E) {
  __shared__ int partial[256];
  int t = threadIdx.x;
  int CH = (B + 255) / 256;
  int b0 = t * CH, b1 = min(B, b0 + CH);
  int tt = 0;
  for (int b = b0; b < b1; b++) {
    int acc = 0;
    for (int w = 0; w < NWG; w++) {
      int idx = b * NWG + w;
      int v = hist[idx];
      hist[idx] = acc;
      acc += v;
    }
    boff[b] = acc;  // temp: bucket total
    tt += acc;
  }
  partial[t] = tt;
  __syncthreads();
  if (t == 0) {
    int acc = 0;
    for (int i = 0; i < 256; i++) { int v = partial[i]; partial[i] = acc; acc += v; }
  }
  __syncthreads();
  int off = partial[t];
  for (int b = b0; b < b1; b++) { int v = boff[b]; boff[b] = off; off += v; }
  if (t == 0) boff[B] = E;
}

// record = (dst_local << 17) | src   (needs N <= 131072)
__global__ __launch_bounds__(256) void k_bfill(const int* __restrict__ src,
                                               const int* __restrict__ dst,
                                               const int* __restrict__ hist,
                                               const int* __restrict__ boff,
                                               int* __restrict__ buck,
                                               int E, int B, int chunk) {
  __shared__ int cur[MAXB];
  int w = blockIdx.x, tid = threadIdx.x;
  for (int b = tid; b < B; b += 256) cur[b] = boff[b] + hist[b * NWG + w];
  __syncthreads();
  int e0 = w * chunk, e1 = min(E, e0 + chunk);
  for (int e = e0 + tid; e < e1; e += 256) {
    int d = dst[e];
    int b = d >> 6, dl = d & 63;
    int p = atomicAdd(&cur[b], 1);
    buck[p] = (dl << 17) | src[e];
  }
}

// ---------------- per-bucket counting sort -> exact per-node CSR ----------------
__global__ __launch_bounds__(256) void k_bsort(const int* __restrict__ buck,
                                               const int* __restrict__ boff,
                                               int* __restrict__ csr,
                                               int* __restrict__ noff,
                                               float* __restrict__ dinv, int N) {
  __shared__ int bin[NB];
  __shared__ int excl[NB];
  int b = blockIdx.x, tid = threadIdx.x;
  if (tid < NB) bin[tid] = 0;
  __syncthreads();
  int r0 = boff[b], r1 = boff[b + 1];
  for (int r = r0 + tid; r < r1; r += 256) atomicAdd(&bin[buck[r] >> 17], 1);
  __syncthreads();
  if (tid == 0) {
    int acc = 0;
    for (int i = 0; i < NB; i++) { excl[i] = acc; acc += bin[i]; }
  }
  __syncthreads();
  if (tid < NB) {
    int n = b * NB + tid;
    if (n < N) {
      dinv[n] = rsqrtf((float)bin[tid] + 1.0f);  // +1 self-loop
      noff[n] = r0 + excl[tid];
    }
  }
  if (b == gridDim.x - 1 && tid == 128) noff[N] = r1;  // r1 == E for last bucket
  __syncthreads();
  if (tid < NB) bin[tid] = excl[tid];  // reuse as cursors
  __syncthreads();
  for (int r = r0 + tid; r < r1; r += 256) {
    int rec = buck[r];
    int p = atomicAdd(&bin[rec >> 17], 1);
    csr[r0 + p] = rec & 0x1FFFF;
  }
}

// ---------------- GEMM1: A = (X @ W1) * dinv[row] ----------------
// #pragma unroll 1 on the k-loop + __launch_bounds__(.,4): the compiler's full
// unroll of the k-loop software-pipelined 8x16 float4 loads -> 256 VGPR ->
// ~100 MB scratch-spill traffic and 10x slowdown (round-6 rocprof).
template <bool ISB>
__device__ __forceinline__ void gemm1_body(const void* __restrict__ Xv,
                                           const float* __restrict__ sW,
                                           const float* __restrict__ dinv,
                                           float* __restrict__ A, int N,
                                           int lane, int wave) {
  const int RPW = 8;
  for (int r0 = (blockIdx.x * 4 + wave) * RPW; r0 < N; r0 += gridDim.x * 4 * RPW) {
    float acc[RPW];
#pragma unroll
    for (int r = 0; r < RPW; r++) acc[r] = 0.f;
#pragma unroll 1
    for (int k4 = 0; k4 < F_IN / 4; ++k4) {
      float w0 = sW[(k4 * 4 + 0) * F_HID + lane];
      float w1 = sW[(k4 * 4 + 1) * F_HID + lane];
      float w2 = sW[(k4 * 4 + 2) * F_HID + lane];
      float w3 = sW[(k4 * 4 + 3) * F_HID + lane];
#pragma unroll
      for (int r = 0; r < RPW; r++) {
        int rr = r0 + r; rr = rr < N ? rr : N - 1;
        float x0, x1, x2, x3;
        if (ISB) {
          ushort4 xv = *reinterpret_cast<const ushort4*>(
              (const unsigned short*)Xv + (size_t)rr * F_IN + k4 * 4);
          x0 = bf2f(xv.x); x1 = bf2f(xv.y); x2 = bf2f(xv.z); x3 = bf2f(xv.w);
        } else {
          float4 xv = *reinterpret_cast<const float4*>(
              (const float*)Xv + (size_t)rr * F_IN + k4 * 4);
          x0 = xv.x; x1 = xv.y; x2 = xv.z; x3 = xv.w;
        }
        acc[r] += x0 * w0 + x1 * w1 + x2 * w2 + x3 * w3;
      }
    }
#pragma unroll
    for (int r = 0; r < RPW; r++) {
      int rr = r0 + r;
      if (rr < N) A[(size_t)rr * F_HID + lane] = acc[r] * dinv[rr];
    }
  }
}

__global__ __launch_bounds__(256, 4) void k_gemm1(const void* __restrict__ Xv,
                                                  const void* __restrict__ Wv,
                                                  const float* __restrict__ dinv,
                                                  float* __restrict__ A, int N,
                                                  const int* __restrict__ flagp) {
  __shared__ float sW[F_IN * F_HID];  // 32 KB
  const bool isb = (*flagp != 0);
  int tid = threadIdx.x;
  for (int t = tid; t < F_IN * F_HID; t += 256)
    sW[t] = isb ? bf2f(((const unsigned short*)Wv)[t]) : ((const float*)Wv)[t];
  __syncthreads();
  const int lane = tid & 63;
  const int wave = tid >> 6;
  if (isb) gemm1_body<true>(Xv, sW, dinv, A, N, lane, wave);
  else     gemm1_body<false>(Xv, sW, dinv, A, N, lane, wave);
}

// ---------------- GEMM2: Bout = (Xin @ W2) * dinv[row] ----------------
__global__ __launch_bounds__(256, 4) void k_gemm2(const float* __restrict__ Xin,
                                                  const void* __restrict__ Wv,
                                                  const float* __restrict__ dinv,
                                                  float* __restrict__ Bout, int N,
                                                  const int* __restrict__ flagp) {
  __shared__ float sW[F_HID * F_HID];  // 16 KB
  const bool isb = (*flagp != 0);
  int tid = threadIdx.x;
  for (int t = tid; t < F_HID * F_HID; t += 256)
    sW[t] = isb ? bf2f(((const unsigned short*)Wv)[t]) : ((const float*)Wv)[t];
  __syncthreads();
  const int lane = tid & 63;
  const int wave = tid >> 6;
  const int RPW = 8;
  for (int r0 = (blockIdx.x * 4 + wave) * RPW; r0 < N; r0 += gridDim.x * 4 * RPW) {
    float acc[RPW];
#pragma unroll
    for (int r = 0; r < RPW; r++) acc[r] = 0.f;
#pragma unroll 1
    for (int k4 = 0; k4 < F_HID / 4; ++k4) {
      float w0 = sW[(k4 * 4 + 0) * F_HID + lane];
      float w1 = sW[(k4 * 4 + 1) * F_HID + lane];
      float w2 = sW[(k4 * 4 + 2) * F_HID + lane];
      float w3 = sW[(k4 * 4 + 3) * F_HID + lane];
#pragma unroll
      for (int r = 0; r < RPW; r++) {
        int rr = r0 + r; rr = rr < N ? rr : N - 1;
        float4 xv = *reinterpret_cast<const float4*>(Xin + (size_t)rr * F_HID + k4 * 4);
        acc[r] += xv.x * w0 + xv.y * w1 + xv.z * w2 + xv.w * w3;
      }
    }
#pragma unroll
    for (int r = 0; r < RPW; r++) {
      int rr = r0 + r;
      if (rr < N) Bout[(size_t)rr * F_HID + lane] = acc[r] * dinv[rr];
    }
  }
}

// ---------------- aggregate (exact CSR, register accumulation) + fused epilogue ----------------
template <bool RELU>
__global__ __launch_bounds__(256) void k_agg(const int* __restrict__ csr,
                                             const int* __restrict__ noff,
                                             const float* __restrict__ H,
                                             const float* __restrict__ dinv,
                                             const void* __restrict__ bias,
                                             float* __restrict__ OUT, int N,
                                             const int* __restrict__ flagp) {
  const bool isb = (*flagp != 0);
  int lane = threadIdx.x & 63;
  int gw = (blockIdx.x * 256 + threadIdx.x) >> 6;
  int nW = (gridDim.x * 256) >> 6;
  float bv = isb ? bf2f(((const unsigned short*)bias)[lane])
                 : ((const float*)bias)[lane];
  for (int n = gw; n < N; n += nW) {
    int start = noff[n], end = noff[n + 1];
    float acc0 = 0.f, acc1 = 0.f;
    for (int e0 = start; e0 < end; e0 += 64) {
      int ee = e0 + lane;
      int idx = (ee < end) ? csr[ee] : 0;
      int m = end - e0; m = m < 64 ? m : 64;
      int k = 0;
      for (; k + 3 < m; k += 4) {
        int s0 = __shfl(idx, k, 64);
        int s1 = __shfl(idx, k + 1, 64);
        int s2 = __shfl(idx, k + 2, 64);
        int s3 = __shfl(idx, k + 3, 64);
        float v0 = H[(size_t)s0 * F_HID + lane];
        float v1 = H[(size_t)s1 * F_HID + lane];
        float v2 = H[(size_t)s2 * F_HID + lane];
        float v3 = H[(size_t)s3 * F_HID + lane];
        acc0 += v0 + v2;
        acc1 += v1 + v3;
      }
      for (; k < m; k++) {
        int s0 = __shfl(idx, k, 64);
        acc0 += H[(size_t)s0 * F_HID + lane];
      }
    }
    float self = H[(size_t)n * F_HID + lane];  // self-loop (already * dinv[n])
    float o = (acc0 + acc1 + self) * dinv[n] + bv;
    if (RELU) o = fmaxf(o, 0.f);
    OUT[(size_t)n * F_HID + lane] = o;
  }
}

// ---------------- PR GEMM: PR[n][0:128] = out2[n] @ Wa ; PR[n][128:256] = out2[n] @ Wb ----------------
__global__ __launch_bounds__(256, 4) void k_gemm_pr(const float* __restrict__ Xin,
                                                    const void* __restrict__ fc1Wv,
                                                    float* __restrict__ PR, int N,
                                                    const int* __restrict__ flagp) {
  __shared__ unsigned short sW[F_HID * 256];  // 32 KB bf16
  const bool isb = (*flagp != 0);
  int tid = threadIdx.x;
  for (int t = tid; t < F_HID * 256; t += 256) {
    int k = t >> 8, h = t & 255;
    int idx = (h < 128) ? (k * 128 + h) : ((64 + k) * 128 + (h - 128));
    sW[t] = isb ? ((const unsigned short*)fc1Wv)[idx]
                : f2bf(((const float*)fc1Wv)[idx]);
  }
  __syncthreads();
  const int lane = tid & 63;
  const int wave = tid >> 6;
  const int RPW = 8;
  for (int r0 = (blockIdx.x * 4 + wave) * RPW; r0 < N; r0 += gridDim.x * 4 * RPW) {
    float acc[RPW][4];
#pragma unroll
    for (int r = 0; r < RPW; r++)
#pragma unroll
      for (int c = 0; c < 4; c++) acc[r][c] = 0.f;
#pragma unroll 1
    for (int k4 = 0; k4 < F_HID / 4; ++k4) {
      float w[4][4];
#pragma unroll
      for (int kk = 0; kk < 4; kk++)
#pragma unroll
        for (int c = 0; c < 4; c++)
          w[kk][c] = bf2f(sW[(k4 * 4 + kk) * 256 + c * 64 + lane]);
#pragma unroll
      for (int r = 0; r < RPW; r++) {
        int rr = r0 + r; rr = rr < N ? rr : N - 1;
        float4 xv = *reinterpret_cast<const float4*>(Xin + (size_t)rr * F_HID + k4 * 4);
#pragma unroll
        for (int c = 0; c < 4; c++)
          acc[r][c] += xv.x * w[0][c] + xv.y * w[1][c] + xv.z * w[2][c] + xv.w * w[3][c];
      }
    }
#pragma unroll
    for (int r = 0; r < RPW; r++) {
      int rr = r0 + r;
      if (rr < N) {
#pragma unroll
        for (int c = 0; c < 4; c++)
          PR[(size_t)rr * 256 + c * 64 + lane] = acc[r][c];
      }
    }
  }
}

// ---------------- query: out[q] = relu(P[i[q]] + R[j[q]] + fc1_b) @ fc2_W + fc2_b ----------------
__global__ __launch_bounds__(256) void k_query(const float* __restrict__ PR,
                                               const int* __restrict__ qi,
                                               const int* __restrict__ qj,
                                               const void* __restrict__ fc1b,
                                               const void* __restrict__ fc2W,
                                               const void* __restrict__ fc2b,
                                               void* __restrict__ out, int Q,
                                               const int* __restrict__ flagp) {
  const bool isb = (*flagp != 0);
  int tid = threadIdx.x;
  int lane = tid & 63;
  int wave = tid >> 6;
  int g = lane >> 4, m = lane & 15;
  float bb[8], w0[8], w1[8];
#pragma unroll
  for (int t = 0; t < 8; t++) {
    int h = m * 8 + t;
    if (isb) {
      bb[t] = bf2f(((const unsigned short*)fc1b)[h]);
      w0[t] = bf2f(((const unsigned short*)fc2W)[h * 2 + 0]);
      w1[t] = bf2f(((const unsigned short*)fc2W)[h * 2 + 1]);
    } else {
      bb[t] = ((const float*)fc1b)[h];
      w0[t] = ((const float*)fc2W)[h * 2 + 0];
      w1[t] = ((const float*)fc2W)[h * 2 + 1];
    }
  }
  float ob0 = isb ? bf2f(((const unsigned short*)fc2b)[0]) : ((const float*)fc2b)[0];
  float ob1 = isb ? bf2f(((const unsigned short*)fc2b)[1]) : ((const float*)fc2b)[1];
  int gw = blockIdx.x * 4 + wave;
  int nW = gridDim.x * 4;
  int nQuad = (Q + 3) >> 2;
  for (int quad = gw; quad < nQuad; quad += nW) {
    int q = quad * 4 + g;
    int qq = q < Q ? q : Q - 1;
    int iq = qi[qq], jq = qj[qq];
    const float4* Pr = reinterpret_cast<const float4*>(PR + (size_t)iq * 256);
    const float4* Rr = reinterpret_cast<const float4*>(PR + (size_t)jq * 256 + 128);
    float4 pa = Pr[m * 2], pb = Pr[m * 2 + 1];
    float4 ra = Rr[m * 2], rb = Rr[m * 2 + 1];
    float h[8] = {pa.x + ra.x, pa.y + ra.y, pa.z + ra.z, pa.w + ra.w,
                  pb.x + rb.x, pb.y + rb.y, pb.z + rb.z, pb.w + rb.w};
    float r0 = 0.f, r1 = 0.f;
#pragma unroll
    for (int t = 0; t < 8; t++) {
      float hv = fmaxf(h[t] + bb[t], 0.f);
      r0 += hv * w0[t];
      r1 += hv * w1[t];
    }
#pragma unroll
    for (int off = 8; off > 0; off >>= 1) {
      r0 += __shfl_xor(r0, off, 16);
      r1 += __shfl_xor(r1, off, 16);
    }
    if (m == 0 && q < Q) {
      if (isb) {
        *reinterpret_cast<ushort2*>((unsigned short*)out + (size_t)q * 2) =
            make_ushort2(f2bf(r0 + ob0), f2bf(r1 + ob1));
      } else {
        *reinterpret_cast<float2*>((float*)out + (size_t)q * 2) =
            make_float2(r0 + ob0, r1 + ob1);
      }
    }
  }
}

extern "C" void kernel_launch(void* const* d_in, const int* in_sizes, int n_in,
                              void* d_out, int out_size, void* d_ws, size_t ws_size,
                              hipStream_t stream) {
  const void* X    = d_in[0];
  const int*  edges= (const int*)d_in[1];
  const int*  qi   = (const int*)d_in[2];
  const int*  qj   = (const int*)d_in[3];
  const void* W1   = d_in[4];
  const void* b1   = d_in[5];
  const void* W2   = d_in[6];
  const void* b2   = d_in[7];
  const void* fc1W = d_in[8];
  const void* fc1b = d_in[9];
  const void* fc2W = d_in[10];
  const void* fc2b = d_in[11];

  const int N = in_sizes[0] / F_IN;
  const int E = in_sizes[1] / 2;
  const int Q = in_sizes[2];
  const int B = (N + NB - 1) / NB;           // buckets (<= MAXB for N <= 131072)
  const int chunk = (E + NWG - 1) / NWG;

  char* ws = (char*)d_ws;
  size_t off = 0;
  auto alloc = [&](size_t bytes) -> void* {
    void* p = ws + off;
    off += (bytes + 255) & ~(size_t)255;
    return p;
  };
  int*   flag = (int*)alloc(4);
  float* dinv = (float*)alloc((size_t)N * 4);
  float* A    = (float*)alloc((size_t)N * F_HID * 4);   // G1 -> G2
  float* Bf   = (float*)alloc((size_t)N * F_HID * 4);   // O1 -> O2
  float* PR   = (float*)alloc((size_t)N * 256 * 4);     // [P | R]
  // bucket/CSR scratch aliases PR (all reads precede gemm_pr's PR writes)
  char* scr = (char*)PR;
  size_t soff = 0;
  auto salloc = [&](size_t bytes) -> void* {
    void* p = scr + soff;
    soff += (bytes + 255) & ~(size_t)255;
    return p;
  };
  int* hist = (int*)salloc((size_t)B * NWG * 4);
  int* boff = (int*)salloc((size_t)(B + 1) * 4);
  int* buck = (int*)salloc((size_t)E * 4);
  int* csr  = (int*)salloc((size_t)E * 4);
  int* noff = (int*)salloc((size_t)(N + 1) * 4);
  (void)ws_size; (void)n_in; (void)out_size;

  const int* esrc = edges;
  const int* edst = edges + E;

  k_detect<<<1, 64, 0, stream>>>((const unsigned int*)X, flag);

  // bucket build + per-bucket counting sort -> exact CSR + noff + dinv
  k_bhist<<<NWG, 256, 0, stream>>>(edst, hist, E, B, chunk);
  k_bscan<<<1, 256, 0, stream>>>(hist, boff, B, E);
  k_bfill<<<NWG, 256, 0, stream>>>(esrc, edst, hist, boff, buck, E, B, chunk);
  k_bsort<<<B, 256, 0, stream>>>(buck, boff, csr, noff, dinv, N);

  // layer 1
  k_gemm1<<<1024, 256, 0, stream>>>(X, W1, dinv, A, N, flag);
  k_agg<true><<<2048, 256, 0, stream>>>(csr, noff, A, dinv, b1, Bf, N, flag);

  // layer 2
  k_gemm2<<<1024, 256, 0, stream>>>(Bf, W2, dinv, A, N, flag);
  k_agg<false><<<2048, 256, 0, stream>>>(csr, noff, A, dinv, b2, Bf, N, flag);

  // MLP factorization: PR = out2 @ [Wa | Wb]  (overwrites bucket scratch — safe)
  k_gemm_pr<<<1024, 256, 0, stream>>>(Bf, fc1W, PR, N, flag);

  // per-query: gather P[i] + R[j], relu, fc2
  k_query<<<4096, 256, 0, stream>>>(PR, qi, qj, fc1b, fc2W, fc2b, d_out, Q, flag);
}

// Round 8
// 776.831 us; speedup vs baseline: 4.3743x; 1.3395x over previous
//
#include <hip/hip_runtime.h>
#include <hip/hip_bf16.h>
#include <hip/hip_fp16.h>
#include <cstdint>

#define F_IN 128
#define F_HID 64
#define NB 64          // nodes per bucket
#define MAXB 2048      // max buckets (N <= 131072)
#define NWG 256        // WGs for hist/fill edge partition

__device__ __forceinline__ float bf2f(unsigned short u) {
  return __uint_as_float(((unsigned int)u) << 16);
}
__device__ __forceinline__ unsigned short f2bf(float f) {
  unsigned int u = __float_as_uint(f);
  u += 0x7FFFu + ((u >> 16) & 1u);   // round-to-nearest-even
  return (unsigned short)(u >> 16);
}
// fp16 storage for internal tensors: half-ulp 2^-11 rel error -- 8x tighter
// than bf16, halves all gather bytes vs fp32.
__device__ __forceinline__ float h2f(unsigned short u) {
  return __half2float(__ushort_as_half(u));
}
__device__ __forceinline__ unsigned short f2h(float f) {
  return __half_as_ushort(__float2half(f));
}

// ---------------- dtype detection (resolved bf16 on this dataset) ----------------
__global__ __launch_bounds__(64) void k_detect(const unsigned int* __restrict__ Xw,
                                               int* __restrict__ flag) {
  int lane = threadIdx.x;
  int cnt = 0;
  for (int t = lane; t < 256; t += 64) {
    unsigned int ex = (Xw[t] >> 7) & 0xFFu;
    cnt += (ex >= 117u && ex <= 137u) ? 1 : 0;
  }
#pragma unroll
  for (int off = 32; off > 0; off >>= 1) cnt += __shfl_xor(cnt, off, 64);
  if (lane == 0) *flag = (cnt >= 128) ? 1 : 0;  // 1 = bf16, 0 = fp32
}

// ---------------- bucket build (no global atomics) ----------------
// hist layout TRANSPOSED vs round 7: hist[w*B + b] so the per-bucket scan
// (thread-per-bucket) is coalesced (round-7 k_bscan serialized 400K strided
// accesses in one WG).
__global__ __launch_bounds__(256) void k_bhist(const int* __restrict__ dst,
                                               int* __restrict__ hist,
                                               int E, int B, int chunk) {
  __shared__ int lh[MAXB];
  int w = blockIdx.x, tid = threadIdx.x;
  for (int b = tid; b < B; b += 256) lh[b] = 0;
  __syncthreads();
  int e0 = w * chunk, e1 = min(E, e0 + chunk);
  for (int e = e0 + tid; e < e1; e += 256) atomicAdd(&lh[dst[e] >> 6], 1);
  __syncthreads();
  for (int b = tid; b < B; b += 256) hist[w * B + b] = lh[b];
}

// thread-per-bucket: exclusive prefix across w (coalesced), bucket totals out
__global__ __launch_bounds__(256) void k_bscan1(int* __restrict__ hist,
                                                int* __restrict__ btot, int B) {
  int b = blockIdx.x * 256 + threadIdx.x;
  if (b >= B) return;
  int acc = 0;
  for (int w = 0; w < NWG; w++) {
    int idx = w * B + b;
    int v = hist[idx];
    hist[idx] = acc;
    acc += v;
  }
  btot[b] = acc;
}

// single WG: exclusive scan of bucket totals -> boff
__global__ __launch_bounds__(256) void k_bscan2(const int* __restrict__ btot,
                                                int* __restrict__ boff, int B, int E) {
  __shared__ int partial[256];
  int t = threadIdx.x;
  int CH = (B + 255) / 256;
  int b0 = t * CH, b1 = min(B, b0 + CH);
  int tt = 0;
  for (int b = b0; b < b1; b++) tt += btot[b];
  partial[t] = tt;
  __syncthreads();
  if (t == 0) {
    int acc = 0;
    for (int i = 0; i < 256; i++) { int v = partial[i]; partial[i] = acc; acc += v; }
  }
  __syncthreads();
  int off = partial[t];
  for (int b = b0; b < b1; b++) { boff[b] = off; off += btot[b]; }
  if (t == 255) boff[B] = E;
}

// record = (dst_local << 17) | src   (needs N <= 131072)
__global__ __launch_bounds__(256) void k_bfill(const int* __restrict__ src,
                                               const int* __restrict__ dst,
                                               const int* __restrict__ hist,
                                               const int* __restrict__ boff,
                                               int* __restrict__ buck,
                                               int E, int B, int chunk) {
  __shared__ int cur[MAXB];
  int w = blockIdx.x, tid = threadIdx.x;
  for (int b = tid; b < B; b += 256) cur[b] = boff[b] + hist[w * B + b];
  __syncthreads();
  int e0 = w * chunk, e1 = min(E, e0 + chunk);
  for (int e = e0 + tid; e < e1; e += 256) {
    int d = dst[e];
    int b = d >> 6, dl = d & 63;
    int p = atomicAdd(&cur[b], 1);
    buck[p] = (dl << 17) | src[e];
  }
}

// ---------------- per-bucket counting sort -> exact per-node CSR ----------------
__global__ __launch_bounds__(256) void k_bsort(const int* __restrict__ buck,
                                               const int* __restrict__ boff,
                                               int* __restrict__ csr,
                                               int* __restrict__ noff,
                                               float* __restrict__ dinv, int N) {
  __shared__ int bin[NB];
  __shared__ int excl[NB];
  int b = blockIdx.x, tid = threadIdx.x;
  if (tid < NB) bin[tid] = 0;
  __syncthreads();
  int r0 = boff[b], r1 = boff[b + 1];
  for (int r = r0 + tid; r < r1; r += 256) atomicAdd(&bin[buck[r] >> 17], 1);
  __syncthreads();
  if (tid == 0) {
    int acc = 0;
    for (int i = 0; i < NB; i++) { excl[i] = acc; acc += bin[i]; }
  }
  __syncthreads();
  if (tid < NB) {
    int n = b * NB + tid;
    if (n < N) {
      dinv[n] = rsqrtf((float)bin[tid] + 1.0f);  // +1 self-loop
      noff[n] = r0 + excl[tid];
    }
  }
  if (b == gridDim.x - 1 && tid == 128) noff[N] = r1;  // r1 == E for last bucket
  __syncthreads();
  if (tid < NB) bin[tid] = excl[tid];  // reuse as cursors
  __syncthreads();
  for (int r = r0 + tid; r < r1; r += 256) {
    int rec = buck[r];
    int p = atomicAdd(&bin[rec >> 17], 1);
    csr[r0 + p] = rec & 0x1FFFF;
  }
}

// ---------------- GEMM1: G = fp16((X @ W1) * dinv[row]) ----------------
// #pragma unroll 1 + __launch_bounds__(.,4): full k-loop unroll spilled to
// 256 VGPR / 100 MB scratch traffic in round 6.
template <bool ISB>
__device__ __forceinline__ void gemm1_body(const void* __restrict__ Xv,
                                           const float* __restrict__ sW,
                                           const float* __restrict__ dinv,
                                           unsigned short* __restrict__ A, int N,
                                           int lane, int wave) {
  const int RPW = 8;
  for (int r0 = (blockIdx.x * 4 + wave) * RPW; r0 < N; r0 += gridDim.x * 4 * RPW) {
    float acc[RPW];
#pragma unroll
    for (int r = 0; r < RPW; r++) acc[r] = 0.f;
#pragma unroll 1
    for (int k4 = 0; k4 < F_IN / 4; ++k4) {
      float w0 = sW[(k4 * 4 + 0) * F_HID + lane];
      float w1 = sW[(k4 * 4 + 1) * F_HID + lane];
      float w2 = sW[(k4 * 4 + 2) * F_HID + lane];
      float w3 = sW[(k4 * 4 + 3) * F_HID + lane];
#pragma unroll
      for (int r = 0; r < RPW; r++) {
        int rr = r0 + r; rr = rr < N ? rr : N - 1;
        float x0, x1, x2, x3;
        if (ISB) {
          ushort4 xv = *reinterpret_cast<const ushort4*>(
              (const unsigned short*)Xv + (size_t)rr * F_IN + k4 * 4);
          x0 = bf2f(xv.x); x1 = bf2f(xv.y); x2 = bf2f(xv.z); x3 = bf2f(xv.w);
        } else {
          float4 xv = *reinterpret_cast<const float4*>(
              (const float*)Xv + (size_t)rr * F_IN + k4 * 4);
          x0 = xv.x; x1 = xv.y; x2 = xv.z; x3 = xv.w;
        }
        acc[r] += x0 * w0 + x1 * w1 + x2 * w2 + x3 * w3;
      }
    }
#pragma unroll
    for (int r = 0; r < RPW; r++) {
      int rr = r0 + r;
      if (rr < N) A[(size_t)rr * F_HID + lane] = f2h(acc[r] * dinv[rr]);
    }
  }
}

__global__ __launch_bounds__(256, 4) void k_gemm1(const void* __restrict__ Xv,
                                                  const void* __restrict__ Wv,
                                                  const float* __restrict__ dinv,
                                                  unsigned short* __restrict__ A, int N,
                                                  const int* __restrict__ flagp) {
  __shared__ float sW[F_IN * F_HID];  // 32 KB
  const bool isb = (*flagp != 0);
  int tid = threadIdx.x;
  for (int t = tid; t < F_IN * F_HID; t += 256)
    sW[t] = isb ? bf2f(((const unsigned short*)Wv)[t]) : ((const float*)Wv)[t];
  __syncthreads();
  const int lane = tid & 63;
  const int wave = tid >> 6;
  if (isb) gemm1_body<true>(Xv, sW, dinv, A, N, lane, wave);
  else     gemm1_body<false>(Xv, sW, dinv, A, N, lane, wave);
}

// ---------------- GEMM2: G = fp16((O1 @ W2) * dinv[row])   (O1 fp16) ----------------
__global__ __launch_bounds__(256, 4) void k_gemm2(const unsigned short* __restrict__ Xin,
                                                  const void* __restrict__ Wv,
                                                  const float* __restrict__ dinv,
                                                  unsigned short* __restrict__ Bout, int N,
                                                  const int* __restrict__ flagp) {
  __shared__ float sW[F_HID * F_HID];  // 16 KB
  const bool isb = (*flagp != 0);
  int tid = threadIdx.x;
  for (int t = tid; t < F_HID * F_HID; t += 256)
    sW[t] = isb ? bf2f(((const unsigned short*)Wv)[t]) : ((const float*)Wv)[t];
  __syncthreads();
  const int lane = tid & 63;
  const int wave = tid >> 6;
  const int RPW = 8;
  for (int r0 = (blockIdx.x * 4 + wave) * RPW; r0 < N; r0 += gridDim.x * 4 * RPW) {
    float acc[RPW];
#pragma unroll
    for (int r = 0; r < RPW; r++) acc[r] = 0.f;
#pragma unroll 1
    for (int k4 = 0; k4 < F_HID / 4; ++k4) {
      float w0 = sW[(k4 * 4 + 0) * F_HID + lane];
      float w1 = sW[(k4 * 4 + 1) * F_HID + lane];
      float w2 = sW[(k4 * 4 + 2) * F_HID + lane];
      float w3 = sW[(k4 * 4 + 3) * F_HID + lane];
#pragma unroll
      for (int r = 0; r < RPW; r++) {
        int rr = r0 + r; rr = rr < N ? rr : N - 1;
        ushort4 xv = *reinterpret_cast<const ushort4*>(Xin + (size_t)rr * F_HID + k4 * 4);
        acc[r] += h2f(xv.x) * w0 + h2f(xv.y) * w1 + h2f(xv.z) * w2 + h2f(xv.w) * w3;
      }
    }
#pragma unroll
    for (int r = 0; r < RPW; r++) {
      int rr = r0 + r;
      if (rr < N) Bout[(size_t)rr * F_HID + lane] = f2h(acc[r] * dinv[rr]);
    }
  }
}

// ---------------- aggregate (exact CSR, register accumulation, fp16 rows) + fused epilogue ----------------
template <bool RELU>
__global__ __launch_bounds__(256) void k_agg(const int* __restrict__ csr,
                                             const int* __restrict__ noff,
                                             const unsigned short* __restrict__ H,
                                             const float* __restrict__ dinv,
                                             const void* __restrict__ bias,
                                             unsigned short* __restrict__ OUT, int N,
                                             const int* __restrict__ flagp) {
  const bool isb = (*flagp != 0);
  int lane = threadIdx.x & 63;
  int gw = (blockIdx.x * 256 + threadIdx.x) >> 6;
  int nW = (gridDim.x * 256) >> 6;
  float bv = isb ? bf2f(((const unsigned short*)bias)[lane])
                 : ((const float*)bias)[lane];
  for (int n = gw; n < N; n += nW) {
    int start = noff[n], end = noff[n + 1];
    float acc0 = 0.f, acc1 = 0.f;
    for (int e0 = start; e0 < end; e0 += 64) {
      int ee = e0 + lane;
      int idx = (ee < end) ? csr[ee] : 0;
      int m = end - e0; m = m < 64 ? m : 64;
      int k = 0;
      for (; k + 3 < m; k += 4) {
        int s0 = __shfl(idx, k, 64);
        int s1 = __shfl(idx, k + 1, 64);
        int s2 = __shfl(idx, k + 2, 64);
        int s3 = __shfl(idx, k + 3, 64);
        float v0 = h2f(H[(size_t)s0 * F_HID + lane]);
        float v1 = h2f(H[(size_t)s1 * F_HID + lane]);
        float v2 = h2f(H[(size_t)s2 * F_HID + lane]);
        float v3 = h2f(H[(size_t)s3 * F_HID + lane]);
        acc0 += v0 + v2;
        acc1 += v1 + v3;
      }
      for (; k < m; k++) {
        int s0 = __shfl(idx, k, 64);
        acc0 += h2f(H[(size_t)s0 * F_HID + lane]);
      }
    }
    float self = h2f(H[(size_t)n * F_HID + lane]);  // self-loop (already * dinv[n])
    float o = (acc0 + acc1 + self) * dinv[n] + bv;
    if (RELU) o = fmaxf(o, 0.f);
    OUT[(size_t)n * F_HID + lane] = f2h(o);
  }
}

// ---------------- PR GEMM: PR fp16; PR[n][0:128] = out2[n]@Wa ; [128:256] = out2[n]@Wb ----------------
__global__ __launch_bounds__(256, 4) void k_gemm_pr(const unsigned short* __restrict__ Xin,
                                                    const void* __restrict__ fc1Wv,
                                                    unsigned short* __restrict__ PR, int N,
                                                    const int* __restrict__ flagp) {
  __shared__ unsigned short sW[F_HID * 256];  // 32 KB bf16
  const bool isb = (*flagp != 0);
  int tid = threadIdx.x;
  for (int t = tid; t < F_HID * 256; t += 256) {
    int k = t >> 8, h = t & 255;
    int idx = (h < 128) ? (k * 128 + h) : ((64 + k) * 128 + (h - 128));
    sW[t] = isb ? ((const unsigned short*)fc1Wv)[idx]
                : f2bf(((const float*)fc1Wv)[idx]);
  }
  __syncthreads();
  const int lane = tid & 63;
  const int wave = tid >> 6;
  const int RPW = 8;
  for (int r0 = (blockIdx.x * 4 + wave) * RPW; r0 < N; r0 += gridDim.x * 4 * RPW) {
    float acc[RPW][4];
#pragma unroll
    for (int r = 0; r < RPW; r++)
#pragma unroll
      for (int c = 0; c < 4; c++) acc[r][c] = 0.f;
#pragma unroll 1
    for (int k4 = 0; k4 < F_HID / 4; ++k4) {
      float w[4][4];
#pragma unroll
      for (int kk = 0; kk < 4; kk++)
#pragma unroll
        for (int c = 0; c < 4; c++)
          w[kk][c] = bf2f(sW[(k4 * 4 + kk) * 256 + c * 64 + lane]);
#pragma unroll
      for (int r = 0; r < RPW; r++) {
        int rr = r0 + r; rr = rr < N ? rr : N - 1;
        ushort4 xv = *reinterpret_cast<const ushort4*>(Xin + (size_t)rr * F_HID + k4 * 4);
        float x0 = h2f(xv.x), x1 = h2f(xv.y), x2 = h2f(xv.z), x3 = h2f(xv.w);
#pragma unroll
        for (int c = 0; c < 4; c++)
          acc[r][c] += x0 * w[0][c] + x1 * w[1][c] + x2 * w[2][c] + x3 * w[3][c];
      }
    }
#pragma unroll
    for (int r = 0; r < RPW; r++) {
      int rr = r0 + r;
      if (rr < N) {
#pragma unroll
        for (int c = 0; c < 4; c++)
          PR[(size_t)rr * 256 + c * 64 + lane] = f2h(acc[r][c]);
      }
    }
  }
}

// ---------------- query: out[q] = relu(P[i[q]] + R[j[q]] + fc1_b) @ fc2_W + fc2_b ----------------
// PR fp16: 16 lanes/query, each lane reads 16 B (8 halves) per side.
__global__ __launch_bounds__(256) void k_query(const unsigned short* __restrict__ PRu,
                                               const int* __restrict__ qi,
                                               const int* __restrict__ qj,
                                               const void* __restrict__ fc1b,
                                               const void* __restrict__ fc2W,
                                               const void* __restrict__ fc2b,
                                               void* __restrict__ out, int Q,
                                               const int* __restrict__ flagp) {
  const bool isb = (*flagp != 0);
  int tid = threadIdx.x;
  int lane = tid & 63;
  int wave = tid >> 6;
  int g = lane >> 4, m = lane & 15;
  float bb[8], w0[8], w1[8];
#pragma unroll
  for (int t = 0; t < 8; t++) {
    int h = m * 8 + t;
    if (isb) {
      bb[t] = bf2f(((const unsigned short*)fc1b)[h]);
      w0[t] = bf2f(((const unsigned short*)fc2W)[h * 2 + 0]);
      w1[t] = bf2f(((const unsigned short*)fc2W)[h * 2 + 1]);
    } else {
      bb[t] = ((const float*)fc1b)[h];
      w0[t] = ((const float*)fc2W)[h * 2 + 0];
      w1[t] = ((const float*)fc2W)[h * 2 + 1];
    }
  }
  float ob0 = isb ? bf2f(((const unsigned short*)fc2b)[0]) : ((const float*)fc2b)[0];
  float ob1 = isb ? bf2f(((const unsigned short*)fc2b)[1]) : ((const float*)fc2b)[1];
  int gw = blockIdx.x * 4 + wave;
  int nW = gridDim.x * 4;
  int nQuad = (Q + 3) >> 2;
  for (int quad = gw; quad < nQuad; quad += nW) {
    int q = quad * 4 + g;
    int qq = q < Q ? q : Q - 1;
    int iq = qi[qq], jq = qj[qq];
    const ushort4* Pr = reinterpret_cast<const ushort4*>(PRu + (size_t)iq * 256) + m * 2;
    const ushort4* Rr = reinterpret_cast<const ushort4*>(PRu + (size_t)jq * 256 + 128) + m * 2;
    ushort4 pa = Pr[0], pb = Pr[1];
    ushort4 ra = Rr[0], rb = Rr[1];
    float h[8] = {h2f(pa.x) + h2f(ra.x), h2f(pa.y) + h2f(ra.y),
                  h2f(pa.z) + h2f(ra.z), h2f(pa.w) + h2f(ra.w),
                  h2f(pb.x) + h2f(rb.x), h2f(pb.y) + h2f(rb.y),
                  h2f(pb.z) + h2f(rb.z), h2f(pb.w) + h2f(rb.w)};
    float r0 = 0.f, r1 = 0.f;
#pragma unroll
    for (int t = 0; t < 8; t++) {
      float hv = fmaxf(h[t] + bb[t], 0.f);
      r0 += hv * w0[t];
      r1 += hv * w1[t];
    }
#pragma unroll
    for (int off = 8; off > 0; off >>= 1) {
      r0 += __shfl_xor(r0, off, 16);
      r1 += __shfl_xor(r1, off, 16);
    }
    if (m == 0 && q < Q) {
      if (isb) {
        *reinterpret_cast<ushort2*>((unsigned short*)out + (size_t)q * 2) =
            make_ushort2(f2bf(r0 + ob0), f2bf(r1 + ob1));
      } else {
        *reinterpret_cast<float2*>((float*)out + (size_t)q * 2) =
            make_float2(r0 + ob0, r1 + ob1);
      }
    }
  }
}

extern "C" void kernel_launch(void* const* d_in, const int* in_sizes, int n_in,
                              void* d_out, int out_size, void* d_ws, size_t ws_size,
                              hipStream_t stream) {
  const void* X    = d_in[0];
  const int*  edges= (const int*)d_in[1];
  const int*  qi   = (const int*)d_in[2];
  const int*  qj   = (const int*)d_in[3];
  const void* W1   = d_in[4];
  const void* b1   = d_in[5];
  const void* W2   = d_in[6];
  const void* b2   = d_in[7];
  const void* fc1W = d_in[8];
  const void* fc1b = d_in[9];
  const void* fc2W = d_in[10];
  const void* fc2b = d_in[11];

  const int N = in_sizes[0] / F_IN;
  const int E = in_sizes[1] / 2;
  const int Q = in_sizes[2];
  const int B = (N + NB - 1) / NB;           // buckets (<= MAXB for N <= 131072)
  const int chunk = (E + NWG - 1) / NWG;

  char* ws = (char*)d_ws;
  size_t off = 0;
  auto alloc = [&](size_t bytes) -> void* {
    void* p = ws + off;
    off += (bytes + 255) & ~(size_t)255;
    return p;
  };
  int*            flag = (int*)alloc(4);
  float*          dinv = (float*)alloc((size_t)N * 4);
  unsigned short* G    = (unsigned short*)alloc((size_t)N * F_HID * 2);  // gemm out (fp16)
  unsigned short* O    = (unsigned short*)alloc((size_t)N * F_HID * 2);  // layer out (fp16)
  unsigned short* PR   = (unsigned short*)alloc((size_t)N * 256 * 2);    // [P | R] fp16
  // bucket/CSR scratch aliases PR (all reads precede gemm_pr's PR writes)
  char* scr = (char*)PR;
  size_t soff = 0;
  auto salloc = [&](size_t bytes) -> void* {
    void* p = scr + soff;
    soff += (bytes + 255) & ~(size_t)255;
    return p;
  };
  int* hist = (int*)salloc((size_t)NWG * B * 4);
  int* btot = (int*)salloc((size_t)(B + 1) * 4);
  int* boff = (int*)salloc((size_t)(B + 1) * 4);
  int* buck = (int*)salloc((size_t)E * 4);
  int* csr  = (int*)salloc((size_t)E * 4);
  int* noff = (int*)salloc((size_t)(N + 1) * 4);
  (void)ws_size; (void)n_in; (void)out_size;

  const int* esrc = edges;
  const int* edst = edges + E;

  k_detect<<<1, 64, 0, stream>>>((const unsigned int*)X, flag);

  // bucket build + per-bucket counting sort -> exact CSR + noff + dinv
  k_bhist<<<NWG, 256, 0, stream>>>(edst, hist, E, B, chunk);
  k_bscan1<<<(B + 255) / 256, 256, 0, stream>>>(hist, btot, B);
  k_bscan2<<<1, 256, 0, stream>>>(btot, boff, B, E);
  k_bfill<<<NWG, 256, 0, stream>>>(esrc, edst, hist, boff, buck, E, B, chunk);
  k_bsort<<<B, 256, 0, stream>>>(buck, boff, csr, noff, dinv, N);

  // layer 1
  k_gemm1<<<1024, 256, 0, stream>>>(X, W1, dinv, G, N, flag);
  k_agg<true><<<2048, 256, 0, stream>>>(csr, noff, G, dinv, b1, O, N, flag);

  // layer 2
  k_gemm2<<<1024, 256, 0, stream>>>(O, W2, dinv, G, N, flag);
  k_agg<false><<<2048, 256, 0, stream>>>(csr, noff, G, dinv, b2, O, N, flag);

  // MLP factorization: PR = out2 @ [Wa | Wb]  (overwrites bucket scratch — safe)
  k_gemm_pr<<<1024, 256, 0, stream>>>(O, fc1W, PR, N, flag);

  // per-query: gather P[i] + R[j], relu, fc2
  k_query<<<4096, 256, 0, stream>>>(PR, qi, qj, fc1b, fc2W, fc2b, d_out, Q, flag);
}

// Round 9
// 650.244 us; speedup vs baseline: 5.2259x; 1.1947x over previous
//
#include <hip/hip_runtime.h>
#include <hip/hip_bf16.h>
#include <hip/hip_fp16.h>
#include <cstdint>

#define F_IN 128
#define F_HID 64
#define NB 64          // nodes per bucket
#define MAXB 2048      // max buckets (N <= 131072)
#define NWG 256        // WGs for hist/fill edge partition

typedef _Float16 half8 __attribute__((ext_vector_type(8)));
typedef float floatx4 __attribute__((ext_vector_type(4)));
union H8 { half8 v; unsigned short u[8]; _Float16 h[8]; };

__device__ __forceinline__ float bf2f(unsigned short u) {
  return __uint_as_float(((unsigned int)u) << 16);
}
__device__ __forceinline__ unsigned short f2bf(float f) {
  unsigned int u = __float_as_uint(f);
  u += 0x7FFFu + ((u >> 16) & 1u);   // round-to-nearest-even
  return (unsigned short)(u >> 16);
}
__device__ __forceinline__ float h2f(unsigned short u) {
  return __half2float(__ushort_as_half(u));
}
__device__ __forceinline__ unsigned short f2h(float f) {
  return __half_as_ushort(__float2half(f));
}

// ---------------- dtype detection (resolved bf16 on this dataset) ----------------
__global__ __launch_bounds__(64) void k_detect(const unsigned int* __restrict__ Xw,
                                               int* __restrict__ flag) {
  int lane = threadIdx.x;
  int cnt = 0;
  for (int t = lane; t < 256; t += 64) {
    unsigned int ex = (Xw[t] >> 7) & 0xFFu;
    cnt += (ex >= 117u && ex <= 137u) ? 1 : 0;
  }
#pragma unroll
  for (int off = 32; off > 0; off >>= 1) cnt += __shfl_xor(cnt, off, 64);
  if (lane == 0) *flag = (cnt >= 128) ? 1 : 0;  // 1 = bf16, 0 = fp32
}

// ---------------- bucket build (no global atomics) ----------------
__global__ __launch_bounds__(256) void k_bhist(const int* __restrict__ dst,
                                               int* __restrict__ hist,
                                               int E, int B, int chunk) {
  __shared__ int lh[MAXB];
  int w = blockIdx.x, tid = threadIdx.x;
  for (int b = tid; b < B; b += 256) lh[b] = 0;
  __syncthreads();
  int e0 = w * chunk, e1 = min(E, e0 + chunk);
  for (int e = e0 + tid; e < e1; e += 256) atomicAdd(&lh[dst[e] >> 6], 1);
  __syncthreads();
  for (int b = tid; b < B; b += 256) hist[w * B + b] = lh[b];
}

__global__ __launch_bounds__(256) void k_bscan1(int* __restrict__ hist,
                                                int* __restrict__ btot, int B) {
  int b = blockIdx.x * 256 + threadIdx.x;
  if (b >= B) return;
  int acc = 0;
  for (int w = 0; w < NWG; w++) {
    int idx = w * B + b;
    int v = hist[idx];
    hist[idx] = acc;
    acc += v;
  }
  btot[b] = acc;
}

__global__ __launch_bounds__(256) void k_bscan2(const int* __restrict__ btot,
                                                int* __restrict__ boff, int B, int E) {
  __shared__ int partial[256];
  int t = threadIdx.x;
  int CH = (B + 255) / 256;
  int b0 = t * CH, b1 = min(B, b0 + CH);
  int tt = 0;
  for (int b = b0; b < b1; b++) tt += btot[b];
  partial[t] = tt;
  __syncthreads();
  if (t == 0) {
    int acc = 0;
    for (int i = 0; i < 256; i++) { int v = partial[i]; partial[i] = acc; acc += v; }
  }
  __syncthreads();
  int off = partial[t];
  for (int b = b0; b < b1; b++) { boff[b] = off; off += btot[b]; }
  if (t == 255) boff[B] = E;
}

// record = (dst_local << 17) | src   (needs N <= 131072)
__global__ __launch_bounds__(256) void k_bfill(const int* __restrict__ src,
                                               const int* __restrict__ dst,
                                               const int* __restrict__ hist,
                                               const int* __restrict__ boff,
                                               int* __restrict__ buck,
                                               int E, int B, int chunk) {
  __shared__ int cur[MAXB];
  int w = blockIdx.x, tid = threadIdx.x;
  for (int b = tid; b < B; b += 256) cur[b] = boff[b] + hist[w * B + b];
  __syncthreads();
  int e0 = w * chunk, e1 = min(E, e0 + chunk);
  for (int e = e0 + tid; e < e1; e += 256) {
    int d = dst[e];
    int b = d >> 6, dl = d & 63;
    int p = atomicAdd(&cur[b], 1);
    buck[p] = (dl << 17) | src[e];
  }
}

// ---------------- per-bucket counting sort -> exact per-node CSR ----------------
__global__ __launch_bounds__(256) void k_bsort(const int* __restrict__ buck,
                                               const int* __restrict__ boff,
                                               int* __restrict__ csr,
                                               int* __restrict__ noff,
                                               float* __restrict__ dinv, int N) {
  __shared__ int bin[NB];
  __shared__ int excl[NB];
  int b = blockIdx.x, tid = threadIdx.x;
  if (tid < NB) bin[tid] = 0;
  __syncthreads();
  int r0 = boff[b], r1 = boff[b + 1];
  for (int r = r0 + tid; r < r1; r += 256) atomicAdd(&bin[buck[r] >> 17], 1);
  __syncthreads();
  if (tid == 0) {
    int acc = 0;
    for (int i = 0; i < NB; i++) { excl[i] = acc; acc += bin[i]; }
  }
  __syncthreads();
  if (tid < NB) {
    int n = b * NB + tid;
    if (n < N) {
      dinv[n] = rsqrtf((float)bin[tid] + 1.0f);  // +1 self-loop
      noff[n] = r0 + excl[tid];
    }
  }
  if (b == gridDim.x - 1 && tid == 128) noff[N] = r1;  // r1 == E for last bucket
  __syncthreads();
  if (tid < NB) bin[tid] = excl[tid];  // reuse as cursors
  __syncthreads();
  for (int r = r0 + tid; r < r1; r += 256) {
    int rec = buck[r];
    int p = atomicAdd(&bin[rec >> 17], 1);
    csr[r0 + p] = rec & 0x1FFFF;
  }
}

// ============ MFMA GEMM layouts (mfma_f32_16x16x32_f16, verified mappings) ============
// A-frag:  A[m = lane&15][k = (lane>>4)*8 + j], j=0..7
// B-frag:  B[k = (lane>>4)*8 + j][n = lane&15]
// D:       D[row = (lane>>4)*4 + reg][col = lane&15]
// All inputs converted to fp16 (bf16->fp16 is mantissa-exact; fp32 accumulate).

// ---------------- GEMM1: G = fp16((X @ W1) * dinv[row]), X bf16 (MFMA) or fp32 (VALU) ----
__device__ __forceinline__ void gemm1_valu(const float* __restrict__ Xf,
                                           const float* __restrict__ sW,
                                           const float* __restrict__ dinv,
                                           unsigned short* __restrict__ A, int N,
                                           int lane, int wave) {
  const int RPW = 8;
  for (int r0 = (blockIdx.x * 4 + wave) * RPW; r0 < N; r0 += gridDim.x * 4 * RPW) {
    float acc[RPW];
#pragma unroll
    for (int r = 0; r < RPW; r++) acc[r] = 0.f;
#pragma unroll 1
    for (int k4 = 0; k4 < F_IN / 4; ++k4) {
      float w0 = sW[(k4 * 4 + 0) * F_HID + lane];
      float w1 = sW[(k4 * 4 + 1) * F_HID + lane];
      float w2 = sW[(k4 * 4 + 2) * F_HID + lane];
      float w3 = sW[(k4 * 4 + 3) * F_HID + lane];
#pragma unroll
      for (int r = 0; r < RPW; r++) {
        int rr = r0 + r; rr = rr < N ? rr : N - 1;
        float4 xv = *reinterpret_cast<const float4*>(Xf + (size_t)rr * F_IN + k4 * 4);
        acc[r] += xv.x * w0 + xv.y * w1 + xv.z * w2 + xv.w * w3;
      }
    }
#pragma unroll
    for (int r = 0; r < RPW; r++) {
      int rr = r0 + r;
      if (rr < N) A[(size_t)rr * F_HID + lane] = f2h(acc[r] * dinv[rr]);
    }
  }
}

__global__ __launch_bounds__(256, 3) void k_gemm1(const void* __restrict__ Xv,
                                                  const void* __restrict__ Wv,
                                                  const float* __restrict__ dinv,
                                                  unsigned short* __restrict__ G, int N,
                                                  const int* __restrict__ flagp) {
  __shared__ float sWf[F_IN * F_HID];  // 32 KB fp32 (VALU path); low 16 KB fp16 (MFMA)
  const bool isb = (*flagp != 0);
  int tid = threadIdx.x;
  if (isb) {
    unsigned short* sWh = (unsigned short*)sWf;
    for (int t = tid; t < F_IN * F_HID; t += 256)
      sWh[t] = f2h(bf2f(((const unsigned short*)Wv)[t]));
  } else {
    for (int t = tid; t < F_IN * F_HID; t += 256) sWf[t] = ((const float*)Wv)[t];
  }
  __syncthreads();
  const int lane = tid & 63, wave = tid >> 6;
  if (!isb) { gemm1_valu((const float*)Xv, sWf, dinv, G, N, lane, wave); return; }

  // MFMA path (bf16 X)
  const unsigned short* X = (const unsigned short*)Xv;
  const unsigned short* sWh = (const unsigned short*)sWf;
  const int m = lane & 15, q = lane >> 4;
  half8 bfrag[4][4];
#pragma unroll
  for (int c = 0; c < 4; c++)
#pragma unroll
    for (int t = 0; t < 4; t++) {
      H8 tmp;
#pragma unroll
      for (int j = 0; j < 8; j++)
        tmp.u[j] = sWh[(c * 32 + q * 8 + j) * F_HID + t * 16 + m];
      bfrag[c][t] = tmp.v;
    }
  int ntiles = (N + 15) >> 4;
  for (int tile = blockIdx.x * 4 + wave; tile < ntiles; tile += gridDim.x * 4) {
    int r0 = tile << 4;
    int rm = r0 + m; rm = rm < N ? rm : N - 1;
    floatx4 acc[4] = {{0.f,0.f,0.f,0.f},{0.f,0.f,0.f,0.f},{0.f,0.f,0.f,0.f},{0.f,0.f,0.f,0.f}};
#pragma unroll
    for (int c = 0; c < 4; c++) {
      H8 raw, a;
      raw.v = *reinterpret_cast<const half8*>(X + (size_t)rm * F_IN + c * 32 + q * 8);
#pragma unroll
      for (int j = 0; j < 8; j++) a.h[j] = (_Float16)bf2f(raw.u[j]);  // exact
#pragma unroll
      for (int t = 0; t < 4; t++)
        acc[t] = __builtin_amdgcn_mfma_f32_16x16x32_f16(a.v, bfrag[c][t], acc[t], 0, 0, 0);
    }
#pragma unroll
    for (int rr = 0; rr < 4; rr++) {
      int grow = r0 + q * 4 + rr;
      if (grow < N) {
        float dv = dinv[grow];
#pragma unroll
        for (int t = 0; t < 4; t++)
          G[(size_t)grow * F_HID + t * 16 + m] = f2h(acc[t][rr] * dv);
      }
    }
  }
}

// ---------------- GEMM2: G = fp16((O @ W2) * dinv[row])   (O fp16, MFMA) ----------------
__global__ __launch_bounds__(256, 4) void k_gemm2(const unsigned short* __restrict__ O,
                                                  const void* __restrict__ Wv,
                                                  const float* __restrict__ dinv,
                                                  unsigned short* __restrict__ G, int N,
                                                  const int* __restrict__ flagp) {
  __shared__ unsigned short sWh[F_HID * F_HID];  // 8 KB fp16
  const bool isb = (*flagp != 0);
  int tid = threadIdx.x;
  for (int t = tid; t < F_HID * F_HID; t += 256)
    sWh[t] = isb ? f2h(bf2f(((const unsigned short*)Wv)[t]))
                 : f2h(((const float*)Wv)[t]);
  __syncthreads();
  const int lane = tid & 63, wave = tid >> 6;
  const int m = lane & 15, q = lane >> 4;
  half8 bfrag[2][4];
#pragma unroll
  for (int c = 0; c < 2; c++)
#pragma unroll
    for (int t = 0; t < 4; t++) {
      H8 tmp;
#pragma unroll
      for (int j = 0; j < 8; j++)
        tmp.u[j] = sWh[(c * 32 + q * 8 + j) * F_HID + t * 16 + m];
      bfrag[c][t] = tmp.v;
    }
  int ntiles = (N + 15) >> 4;
  for (int tile = blockIdx.x * 4 + wave; tile < ntiles; tile += gridDim.x * 4) {
    int r0 = tile << 4;
    int rm = r0 + m; rm = rm < N ? rm : N - 1;
    floatx4 acc[4] = {{0.f,0.f,0.f,0.f},{0.f,0.f,0.f,0.f},{0.f,0.f,0.f,0.f},{0.f,0.f,0.f,0.f}};
#pragma unroll
    for (int c = 0; c < 2; c++) {
      half8 a = *reinterpret_cast<const half8*>(O + (size_t)rm * F_HID + c * 32 + q * 8);
#pragma unroll
      for (int t = 0; t < 4; t++)
        acc[t] = __builtin_amdgcn_mfma_f32_16x16x32_f16(a, bfrag[c][t], acc[t], 0, 0, 0);
    }
#pragma unroll
    for (int rr = 0; rr < 4; rr++) {
      int grow = r0 + q * 4 + rr;
      if (grow < N) {
        float dv = dinv[grow];
#pragma unroll
        for (int t = 0; t < 4; t++)
          G[(size_t)grow * F_HID + t * 16 + m] = f2h(acc[t][rr] * dv);
      }
    }
  }
}

// ---------------- aggregate (exact CSR, register accumulation, fp16 rows) + fused epilogue ----------------
template <bool RELU>
__global__ __launch_bounds__(256) void k_agg(const int* __restrict__ csr,
                                             const int* __restrict__ noff,
                                             const unsigned short* __restrict__ H,
                                             const float* __restrict__ dinv,
                                             const void* __restrict__ bias,
                                             unsigned short* __restrict__ OUT, int N,
                                             const int* __restrict__ flagp) {
  const bool isb = (*flagp != 0);
  int lane = threadIdx.x & 63;
  int gw = (blockIdx.x * 256 + threadIdx.x) >> 6;
  int nW = (gridDim.x * 256) >> 6;
  float bv = isb ? bf2f(((const unsigned short*)bias)[lane])
                 : ((const float*)bias)[lane];
  for (int n = gw; n < N; n += nW) {
    int start = noff[n], end = noff[n + 1];
    float acc0 = 0.f, acc1 = 0.f;
    for (int e0 = start; e0 < end; e0 += 64) {
      int ee = e0 + lane;
      int idx = (ee < end) ? csr[ee] : 0;
      int m = end - e0; m = m < 64 ? m : 64;
      int k = 0;
      for (; k + 3 < m; k += 4) {
        int s0 = __shfl(idx, k, 64);
        int s1 = __shfl(idx, k + 1, 64);
        int s2 = __shfl(idx, k + 2, 64);
        int s3 = __shfl(idx, k + 3, 64);
        float v0 = h2f(H[(size_t)s0 * F_HID + lane]);
        float v1 = h2f(H[(size_t)s1 * F_HID + lane]);
        float v2 = h2f(H[(size_t)s2 * F_HID + lane]);
        float v3 = h2f(H[(size_t)s3 * F_HID + lane]);
        acc0 += v0 + v2;
        acc1 += v1 + v3;
      }
      for (; k < m; k++) {
        int s0 = __shfl(idx, k, 64);
        acc0 += h2f(H[(size_t)s0 * F_HID + lane]);
      }
    }
    float self = h2f(H[(size_t)n * F_HID + lane]);  // self-loop (already * dinv[n])
    float o = (acc0 + acc1 + self) * dinv[n] + bv;
    if (RELU) o = fmaxf(o, 0.f);
    OUT[(size_t)n * F_HID + lane] = f2h(o);
  }
}

// ---------------- PR GEMM (MFMA): PR[n][0:128]=O[n]@Wa ; [128:256]=O[n]@Wb, fp16 out ----
// Block handles output-column group g = blockIdx&3 (64 cols); B-frags register-resident.
__global__ __launch_bounds__(256, 4) void k_gemm_pr(const unsigned short* __restrict__ O,
                                                    const void* __restrict__ fc1Wv,
                                                    unsigned short* __restrict__ PR, int N,
                                                    const int* __restrict__ flagp) {
  __shared__ unsigned short sWh[F_HID * 64];  // 8 KB fp16 slice
  const bool isb = (*flagp != 0);
  const int g = blockIdx.x & 3;
  const int rowoff = (g & 2) ? 64 : 0;   // g>=2 -> Wb half (fc1W rows 64..127)
  const int coloff = (g & 1) * 64;
  int tid = threadIdx.x;
  for (int t = tid; t < F_HID * 64; t += 256) {
    int k = t >> 6, c = t & 63;
    int idx = (rowoff + k) * 128 + coloff + c;
    sWh[t] = isb ? f2h(bf2f(((const unsigned short*)fc1Wv)[idx]))
                 : f2h(((const float*)fc1Wv)[idx]);
  }
  __syncthreads();
  const int lane = tid & 63, wave = tid >> 6;
  const int m = lane & 15, q = lane >> 4;
  half8 bfrag[2][4];
#pragma unroll
  for (int c = 0; c < 2; c++)
#pragma unroll
    for (int t = 0; t < 4; t++) {
      H8 tmp;
#pragma unroll
      for (int j = 0; j < 8; j++)
        tmp.u[j] = sWh[(c * 32 + q * 8 + j) * 64 + t * 16 + m];
      bfrag[c][t] = tmp.v;
    }
  int ntiles = (N + 15) >> 4;
  int tstride = (gridDim.x >> 2) * 4;
  for (int tile = (blockIdx.x >> 2) * 4 + wave; tile < ntiles; tile += tstride) {
    int r0 = tile << 4;
    int rm = r0 + m; rm = rm < N ? rm : N - 1;
    floatx4 acc[4] = {{0.f,0.f,0.f,0.f},{0.f,0.f,0.f,0.f},{0.f,0.f,0.f,0.f},{0.f,0.f,0.f,0.f}};
#pragma unroll
    for (int c = 0; c < 2; c++) {
      half8 a = *reinterpret_cast<const half8*>(O + (size_t)rm * F_HID + c * 32 + q * 8);
#pragma unroll
      for (int t = 0; t < 4; t++)
        acc[t] = __builtin_amdgcn_mfma_f32_16x16x32_f16(a, bfrag[c][t], acc[t], 0, 0, 0);
    }
#pragma unroll
    for (int rr = 0; rr < 4; rr++) {
      int grow = r0 + q * 4 + rr;
      if (grow < N) {
#pragma unroll
        for (int t = 0; t < 4; t++)
          PR[(size_t)grow * 256 + g * 64 + t * 16 + m] = f2h(acc[t][rr]);
      }
    }
  }
}

// ---------------- query: out[q] = relu(P[i[q]] + R[j[q]] + fc1_b) @ fc2_W + fc2_b ----------------
__global__ __launch_bounds__(256) void k_query(const unsigned short* __restrict__ PRu,
                                               const int* __restrict__ qi,
                                               const int* __restrict__ qj,
                                               const void* __restrict__ fc1b,
                                               const void* __restrict__ fc2W,
                                               const void* __restrict__ fc2b,
                                               void* __restrict__ out, int Q,
                                               const int* __restrict__ flagp) {
  const bool isb = (*flagp != 0);
  int tid = threadIdx.x;
  int lane = tid & 63;
  int wave = tid >> 6;
  int g = lane >> 4, m = lane & 15;
  float bb[8], w0[8], w1[8];
#pragma unroll
  for (int t = 0; t < 8; t++) {
    int h = m * 8 + t;
    if (isb) {
      bb[t] = bf2f(((const unsigned short*)fc1b)[h]);
      w0[t] = bf2f(((const unsigned short*)fc2W)[h * 2 + 0]);
      w1[t] = bf2f(((const unsigned short*)fc2W)[h * 2 + 1]);
    } else {
      bb[t] = ((const float*)fc1b)[h];
      w0[t] = ((const float*)fc2W)[h * 2 + 0];
      w1[t] = ((const float*)fc2W)[h * 2 + 1];
    }
  }
  float ob0 = isb ? bf2f(((const unsigned short*)fc2b)[0]) : ((const float*)fc2b)[0];
  float ob1 = isb ? bf2f(((const unsigned short*)fc2b)[1]) : ((const float*)fc2b)[1];
  int gw = blockIdx.x * 4 + wave;
  int nW = gridDim.x * 4;
  int nQuad = (Q + 3) >> 2;
  for (int quad = gw; quad < nQuad; quad += nW) {
    int q = quad * 4 + g;
    int qq = q < Q ? q : Q - 1;
    int iq = qi[qq], jq = qj[qq];
    const ushort4* Pr = reinterpret_cast<const ushort4*>(PRu + (size_t)iq * 256) + m * 2;
    const ushort4* Rr = reinterpret_cast<const ushort4*>(PRu + (size_t)jq * 256 + 128) + m * 2;
    ushort4 pa = Pr[0], pb = Pr[1];
    ushort4 ra = Rr[0], rb = Rr[1];
    float h[8] = {h2f(pa.x) + h2f(ra.x), h2f(pa.y) + h2f(ra.y),
                  h2f(pa.z) + h2f(ra.z), h2f(pa.w) + h2f(ra.w),
                  h2f(pb.x) + h2f(rb.x), h2f(pb.y) + h2f(rb.y),
                  h2f(pb.z) + h2f(rb.z), h2f(pb.w) + h2f(rb.w)};
    float r0 = 0.f, r1 = 0.f;
#pragma unroll
    for (int t = 0; t < 8; t++) {
      float hv = fmaxf(h[t] + bb[t], 0.f);
      r0 += hv * w0[t];
      r1 += hv * w1[t];
    }
#pragma unroll
    for (int off = 8; off > 0; off >>= 1) {
      r0 += __shfl_xor(r0, off, 16);
      r1 += __shfl_xor(r1, off, 16);
    }
    if (m == 0 && q < Q) {
      if (isb) {
        *reinterpret_cast<ushort2*>((unsigned short*)out + (size_t)q * 2) =
            make_ushort2(f2bf(r0 + ob0), f2bf(r1 + ob1));
      } else {
        *reinterpret_cast<float2*>((float*)out + (size_t)q * 2) =
            make_float2(r0 + ob0, r1 + ob1);
      }
    }
  }
}

extern "C" void kernel_launch(void* const* d_in, const int* in_sizes, int n_in,
                              void* d_out, int out_size, void* d_ws, size_t ws_size,
                              hipStream_t stream) {
  const void* X    = d_in[0];
  const int*  edges= (const int*)d_in[1];
  const int*  qi   = (const int*)d_in[2];
  const int*  qj   = (const int*)d_in[3];
  const void* W1   = d_in[4];
  const void* b1   = d_in[5];
  const void* W2   = d_in[6];
  const void* b2   = d_in[7];
  const void* fc1W = d_in[8];
  const void* fc1b = d_in[9];
  const void* fc2W = d_in[10];
  const void* fc2b = d_in[11];

  const int N = in_sizes[0] / F_IN;
  const int E = in_sizes[1] / 2;
  const int Q = in_sizes[2];
  const int B = (N + NB - 1) / NB;           // buckets (<= MAXB for N <= 131072)
  const int chunk = (E + NWG - 1) / NWG;

  char* ws = (char*)d_ws;
  size_t off = 0;
  auto alloc = [&](size_t bytes) -> void* {
    void* p = ws + off;
    off += (bytes + 255) & ~(size_t)255;
    return p;
  };
  int*            flag = (int*)alloc(4);
  float*          dinv = (float*)alloc((size_t)N * 4);
  unsigned short* G    = (unsigned short*)alloc((size_t)N * F_HID * 2);  // gemm out (fp16)
  unsigned short* O    = (unsigned short*)alloc((size_t)N * F_HID * 2);  // layer out (fp16)
  unsigned short* PR   = (unsigned short*)alloc((size_t)N * 256 * 2);    // [P | R] fp16
  // bucket/CSR scratch aliases PR (all reads precede gemm_pr's PR writes)
  char* scr = (char*)PR;
  size_t soff = 0;
  auto salloc = [&](size_t bytes) -> void* {
    void* p = scr + soff;
    soff += (bytes + 255) & ~(size_t)255;
    return p;
  };
  int* hist = (int*)salloc((size_t)NWG * B * 4);
  int* btot = (int*)salloc((size_t)(B + 1) * 4);
  int* boff = (int*)salloc((size_t)(B + 1) * 4);
  int* buck = (int*)salloc((size_t)E * 4);
  int* csr  = (int*)salloc((size_t)E * 4);
  int* noff = (int*)salloc((size_t)(N + 1) * 4);
  (void)ws_size; (void)n_in; (void)out_size;

  const int* esrc = edges;
  const int* edst = edges + E;

  k_detect<<<1, 64, 0, stream>>>((const unsigned int*)X, flag);

  // bucket build + per-bucket counting sort -> exact CSR + noff + dinv
  k_bhist<<<NWG, 256, 0, stream>>>(edst, hist, E, B, chunk);
  k_bscan1<<<(B + 255) / 256, 256, 0, stream>>>(hist, btot, B);
  k_bscan2<<<1, 256, 0, stream>>>(btot, boff, B, E);
  k_bfill<<<NWG, 256, 0, stream>>>(esrc, edst, hist, boff, buck, E, B, chunk);
  k_bsort<<<B, 256, 0, stream>>>(buck, boff, csr, noff, dinv, N);

  // layer 1
  k_gemm1<<<1024, 256, 0, stream>>>(X, W1, dinv, G, N, flag);
  k_agg<true><<<2048, 256, 0, stream>>>(csr, noff, G, dinv, b1, O, N, flag);

  // layer 2
  k_gemm2<<<1024, 256, 0, stream>>>(O, W2, dinv, G, N, flag);
  k_agg<false><<<2048, 256, 0, stream>>>(csr, noff, G, dinv, b2, O, N, flag);

  // MLP factorization: PR = out2 @ [Wa | Wb]  (overwrites bucket scratch — safe)
  k_gemm_pr<<<1024, 256, 0, stream>>>(O, fc1W, PR, N, flag);

  // per-query: gather P[i] + R[j], relu, fc2
  k_query<<<4096, 256, 0, stream>>>(PR, qi, qj, fc1b, fc2W, fc2b, d_out, Q, flag);
}

// Round 10
// 644.865 us; speedup vs baseline: 5.2695x; 1.0083x over previous
//
#include <hip/hip_runtime.h>
#include <hip/hip_bf16.h>
#include <hip/hip_fp16.h>
#include <cstdint>

#define F_IN 128
#define F_HID 64
#define NB 64          // nodes per bucket
#define MAXB 2048      // max buckets (N <= 131072)
#define NWG 256        // WGs for hist/fill edge partition

typedef _Float16 half8 __attribute__((ext_vector_type(8)));
typedef float floatx4 __attribute__((ext_vector_type(4)));

__device__ __forceinline__ float bf2f(unsigned short u) {
  return __uint_as_float(((unsigned int)u) << 16);
}
__device__ __forceinline__ unsigned short f2bf(float f) {
  unsigned int u = __float_as_uint(f);
  u += 0x7FFFu + ((u >> 16) & 1u);   // round-to-nearest-even
  return (unsigned short)(u >> 16);
}
__device__ __forceinline__ float h2f(unsigned short u) {
  return __half2float(__ushort_as_half(u));
}
__device__ __forceinline__ unsigned short f2h(float f) {
  return __half_as_ushort(__float2half(f));
}

// ---------------- dtype detection (resolved bf16 on this dataset) ----------------
__global__ __launch_bounds__(64) void k_detect(const unsigned int* __restrict__ Xw,
                                               int* __restrict__ flag) {
  int lane = threadIdx.x;
  int cnt = 0;
  for (int t = lane; t < 256; t += 64) {
    unsigned int ex = (Xw[t] >> 7) & 0xFFu;
    cnt += (ex >= 117u && ex <= 137u) ? 1 : 0;
  }
#pragma unroll
  for (int off = 32; off > 0; off >>= 1) cnt += __shfl_xor(cnt, off, 64);
  if (lane == 0) *flag = (cnt >= 128) ? 1 : 0;  // 1 = bf16, 0 = fp32
}

// ---------------- bucket build (no global atomics) ----------------
__global__ __launch_bounds__(256) void k_bhist(const int* __restrict__ dst,
                                               int* __restrict__ hist,
                                               int E, int B, int chunk) {
  __shared__ int lh[MAXB];
  int w = blockIdx.x, tid = threadIdx.x;
  for (int b = tid; b < B; b += 256) lh[b] = 0;
  __syncthreads();
  int e0 = w * chunk, e1 = min(E, e0 + chunk);
  for (int e = e0 + tid; e < e1; e += 256) atomicAdd(&lh[dst[e] >> 6], 1);
  __syncthreads();
  for (int b = tid; b < B; b += 256) hist[w * B + b] = lh[b];
}

__global__ __launch_bounds__(256) void k_bscan1(int* __restrict__ hist,
                                                int* __restrict__ btot, int B) {
  int b = blockIdx.x * 256 + threadIdx.x;
  if (b >= B) return;
  int acc = 0;
  for (int w = 0; w < NWG; w++) {
    int idx = w * B + b;
    int v = hist[idx];
    hist[idx] = acc;
    acc += v;
  }
  btot[b] = acc;
}

__global__ __launch_bounds__(256) void k_bscan2(const int* __restrict__ btot,
                                                int* __restrict__ boff, int B, int E) {
  __shared__ int partial[256];
  int t = threadIdx.x;
  int CH = (B + 255) / 256;
  int b0 = t * CH, b1 = min(B, b0 + CH);
  int tt = 0;
  for (int b = b0; b < b1; b++) tt += btot[b];
  partial[t] = tt;
  __syncthreads();
  if (t == 0) {
    int acc = 0;
    for (int i = 0; i < 256; i++) { int v = partial[i]; partial[i] = acc; acc += v; }
  }
  __syncthreads();
  int off = partial[t];
  for (int b = b0; b < b1; b++) { boff[b] = off; off += btot[b]; }
  if (t == 255) boff[B] = E;
}

// record = (dst_local << 17) | src   (needs N <= 131072)
__global__ __launch_bounds__(256) void k_bfill(const int* __restrict__ src,
                                               const int* __restrict__ dst,
                                               const int* __restrict__ hist,
                                               const int* __restrict__ boff,
                                               int* __restrict__ buck,
                                               int E, int B, int chunk) {
  __shared__ int cur[MAXB];
  int w = blockIdx.x, tid = threadIdx.x;
  for (int b = tid; b < B; b += 256) cur[b] = boff[b] + hist[w * B + b];
  __syncthreads();
  int e0 = w * chunk, e1 = min(E, e0 + chunk);
  for (int e = e0 + tid; e < e1; e += 256) {
    int d = dst[e];
    int b = d >> 6, dl = d & 63;
    int p = atomicAdd(&cur[b], 1);
    buck[p] = (dl << 17) | src[e];
  }
}

// ---------------- per-bucket counting sort -> exact per-node CSR ----------------
__global__ __launch_bounds__(256) void k_bsort(const int* __restrict__ buck,
                                               const int* __restrict__ boff,
                                               int* __restrict__ csr,
                                               int* __restrict__ noff,
                                               float* __restrict__ dinv, int N) {
  __shared__ int bin[NB];
  __shared__ int excl[NB];
  int b = blockIdx.x, tid = threadIdx.x;
  if (tid < NB) bin[tid] = 0;
  __syncthreads();
  int r0 = boff[b], r1 = boff[b + 1];
  for (int r = r0 + tid; r < r1; r += 256) atomicAdd(&bin[buck[r] >> 17], 1);
  __syncthreads();
  if (tid == 0) {
    int acc = 0;
    for (int i = 0; i < NB; i++) { excl[i] = acc; acc += bin[i]; }
  }
  __syncthreads();
  if (tid < NB) {
    int n = b * NB + tid;
    if (n < N) {
      dinv[n] = rsqrtf((float)bin[tid] + 1.0f);  // +1 self-loop
      noff[n] = r0 + excl[tid];
    }
  }
  if (b == gridDim.x - 1 && tid == 128) noff[N] = r1;  // r1 == E for last bucket
  __syncthreads();
  if (tid < NB) bin[tid] = excl[tid];  // reuse as cursors
  __syncthreads();
  for (int r = r0 + tid; r < r1; r += 256) {
    int rec = buck[r];
    int p = atomicAdd(&bin[rec >> 17], 1);
    csr[r0 + p] = rec & 0x1FFFF;
  }
}

// ============ MFMA GEMM (mfma_f32_16x16x32_f16) ============
// A-frag:  A[m = lane&15][k = (lane>>4)*8 + j]
// B-frag:  B[k = (lane>>4)*8 + j][n = lane&15]
// D:       D[row = (lane>>4)*4 + reg][col = lane&15]
// Weights staged in LDS in FRAGMENT ORDER so each lane's B-frag is one
// contiguous ds_read_b128 (round-9's union-punned per-element gather defeated
// SROA -> fragments demoted from registers; VGPR_Count=60 < the 64 needed).
// frag-order dest (ushorts) for W element (k,n), ncols=64:
//   c=k>>5, q=(k>>3)&3, j=k&7, t=n>>4, m=n&15 -> ((c*4+t)*64 + q*16+m)*8 + j

// ---------------- GEMM1: G = fp16((X @ W1) * dinv[row]), X bf16 (MFMA) or fp32 (VALU) ----
__device__ __forceinline__ void gemm1_valu(const float* __restrict__ Xf,
                                           const float* __restrict__ sW,
                                           const float* __restrict__ dinv,
                                           unsigned short* __restrict__ A, int N,
                                           int lane, int wave) {
  const int RPW = 8;
  for (int r0 = (blockIdx.x * 4 + wave) * RPW; r0 < N; r0 += gridDim.x * 4 * RPW) {
    float acc[RPW];
#pragma unroll
    for (int r = 0; r < RPW; r++) acc[r] = 0.f;
#pragma unroll 1
    for (int k4 = 0; k4 < F_IN / 4; ++k4) {
      float w0 = sW[(k4 * 4 + 0) * F_HID + lane];
      float w1 = sW[(k4 * 4 + 1) * F_HID + lane];
      float w2 = sW[(k4 * 4 + 2) * F_HID + lane];
      float w3 = sW[(k4 * 4 + 3) * F_HID + lane];
#pragma unroll
      for (int r = 0; r < RPW; r++) {
        int rr = r0 + r; rr = rr < N ? rr : N - 1;
        float4 xv = *reinterpret_cast<const float4*>(Xf + (size_t)rr * F_IN + k4 * 4);
        acc[r] += xv.x * w0 + xv.y * w1 + xv.z * w2 + xv.w * w3;
      }
    }
#pragma unroll
    for (int r = 0; r < RPW; r++) {
      int rr = r0 + r;
      if (rr < N) A[(size_t)rr * F_HID + lane] = f2h(acc[r] * dinv[rr]);
    }
  }
}

__global__ __launch_bounds__(256, 3) void k_gemm1(const void* __restrict__ Xv,
                                                  const void* __restrict__ Wv,
                                                  const float* __restrict__ dinv,
                                                  unsigned short* __restrict__ G, int N,
                                                  const int* __restrict__ flagp) {
  __shared__ float sWf[F_IN * F_HID];  // 32 KB fp32 (VALU); low 16 KB = frag-order fp16 (MFMA)
  const bool isb = (*flagp != 0);
  int tid = threadIdx.x;
  if (isb) {
    unsigned short* sWh = (unsigned short*)sWf;
    for (int e = tid; e < F_IN * F_HID; e += 256) {
      int k = e >> 6, n = e & 63;
      int c = k >> 5, q = (k >> 3) & 3, j = k & 7, t = n >> 4, m = n & 15;
      sWh[((c * 4 + t) * 64 + q * 16 + m) * 8 + j] =
          f2h(bf2f(((const unsigned short*)Wv)[e]));
    }
  } else {
    for (int e = tid; e < F_IN * F_HID; e += 256) sWf[e] = ((const float*)Wv)[e];
  }
  __syncthreads();
  const int lane = tid & 63, wave = tid >> 6;
  if (!isb) { gemm1_valu((const float*)Xv, sWf, dinv, G, N, lane, wave); return; }

  // MFMA path (bf16 X)
  const unsigned short* X = (const unsigned short*)Xv;
  const unsigned short* sWh = (const unsigned short*)sWf;
  const int m = lane & 15, q = lane >> 4;
  half8 bfrag[4][4];
#pragma unroll
  for (int c = 0; c < 4; c++)
#pragma unroll
    for (int t = 0; t < 4; t++)
      bfrag[c][t] = *reinterpret_cast<const half8*>(sWh + ((c * 4 + t) * 64 + lane) * 8);
  int ntiles = (N + 15) >> 4;
  for (int tile = blockIdx.x * 4 + wave; tile < ntiles; tile += gridDim.x * 4) {
    int r0 = tile << 4;
    int rm = r0 + m; rm = rm < N ? rm : N - 1;
    const uint4* xrow = reinterpret_cast<const uint4*>(X + (size_t)rm * F_IN);
    floatx4 acc[4] = {{0.f,0.f,0.f,0.f},{0.f,0.f,0.f,0.f},{0.f,0.f,0.f,0.f},{0.f,0.f,0.f,0.f}};
#pragma unroll
    for (int c = 0; c < 4; c++) {
      uint4 d = xrow[c * 4 + q];
      half8 a;
      a[0] = (_Float16)__uint_as_float(d.x << 16);
      a[1] = (_Float16)__uint_as_float(d.x & 0xFFFF0000u);
      a[2] = (_Float16)__uint_as_float(d.y << 16);
      a[3] = (_Float16)__uint_as_float(d.y & 0xFFFF0000u);
      a[4] = (_Float16)__uint_as_float(d.z << 16);
      a[5] = (_Float16)__uint_as_float(d.z & 0xFFFF0000u);
      a[6] = (_Float16)__uint_as_float(d.w << 16);
      a[7] = (_Float16)__uint_as_float(d.w & 0xFFFF0000u);
#pragma unroll
      for (int t = 0; t < 4; t++)
        acc[t] = __builtin_amdgcn_mfma_f32_16x16x32_f16(a, bfrag[c][t], acc[t], 0, 0, 0);
    }
#pragma unroll
    for (int rr = 0; rr < 4; rr++) {
      int grow = r0 + q * 4 + rr;
      if (grow < N) {
        float dv = dinv[grow];
#pragma unroll
        for (int t = 0; t < 4; t++)
          G[(size_t)grow * F_HID + t * 16 + m] = f2h(acc[t][rr] * dv);
      }
    }
  }
}

// ---------------- GEMM2: G = fp16((O @ W2) * dinv[row])   (O fp16, MFMA) ----------------
__global__ __launch_bounds__(256, 4) void k_gemm2(const unsigned short* __restrict__ O,
                                                  const void* __restrict__ Wv,
                                                  const float* __restrict__ dinv,
                                                  unsigned short* __restrict__ G, int N,
                                                  const int* __restrict__ flagp) {
  __shared__ unsigned short sWh[F_HID * F_HID];  // 8 KB fp16, fragment order
  const bool isb = (*flagp != 0);
  int tid = threadIdx.x;
  for (int e = tid; e < F_HID * F_HID; e += 256) {
    int k = e >> 6, n = e & 63;
    int c = k >> 5, q = (k >> 3) & 3, j = k & 7, t = n >> 4, m = n & 15;
    sWh[((c * 4 + t) * 64 + q * 16 + m) * 8 + j] =
        isb ? f2h(bf2f(((const unsigned short*)Wv)[e]))
            : f2h(((const float*)Wv)[e]);
  }
  __syncthreads();
  const int lane = tid & 63, wave = tid >> 6;
  const int m = lane & 15, q = lane >> 4;
  half8 bfrag[2][4];
#pragma unroll
  for (int c = 0; c < 2; c++)
#pragma unroll
    for (int t = 0; t < 4; t++)
      bfrag[c][t] = *reinterpret_cast<const half8*>(sWh + ((c * 4 + t) * 64 + lane) * 8);
  int ntiles = (N + 15) >> 4;
  for (int tile = blockIdx.x * 4 + wave; tile < ntiles; tile += gridDim.x * 4) {
    int r0 = tile << 4;
    int rm = r0 + m; rm = rm < N ? rm : N - 1;
    floatx4 acc[4] = {{0.f,0.f,0.f,0.f},{0.f,0.f,0.f,0.f},{0.f,0.f,0.f,0.f},{0.f,0.f,0.f,0.f}};
#pragma unroll
    for (int c = 0; c < 2; c++) {
      half8 a = *reinterpret_cast<const half8*>(O + (size_t)rm * F_HID + c * 32 + q * 8);
#pragma unroll
      for (int t = 0; t < 4; t++)
        acc[t] = __builtin_amdgcn_mfma_f32_16x16x32_f16(a, bfrag[c][t], acc[t], 0, 0, 0);
    }
#pragma unroll
    for (int rr = 0; rr < 4; rr++) {
      int grow = r0 + q * 4 + rr;
      if (grow < N) {
        float dv = dinv[grow];
#pragma unroll
        for (int t = 0; t < 4; t++)
          G[(size_t)grow * F_HID + t * 16 + m] = f2h(acc[t][rr] * dv);
      }
    }
  }
}

// ---------------- aggregate (exact CSR, register accumulation, fp16 rows) + fused epilogue ----------------
template <bool RELU>
__global__ __launch_bounds__(256) void k_agg(const int* __restrict__ csr,
                                             const int* __restrict__ noff,
                                             const unsigned short* __restrict__ H,
                                             const float* __restrict__ dinv,
                                             const void* __restrict__ bias,
                                             unsigned short* __restrict__ OUT, int N,
                                             const int* __restrict__ flagp) {
  const bool isb = (*flagp != 0);
  int lane = threadIdx.x & 63;
  int gw = (blockIdx.x * 256 + threadIdx.x) >> 6;
  int nW = (gridDim.x * 256) >> 6;
  float bv = isb ? bf2f(((const unsigned short*)bias)[lane])
                 : ((const float*)bias)[lane];
  for (int n = gw; n < N; n += nW) {
    int start = noff[n], end = noff[n + 1];
    float acc0 = 0.f, acc1 = 0.f;
    for (int e0 = start; e0 < end; e0 += 64) {
      int ee = e0 + lane;
      int idx = (ee < end) ? csr[ee] : 0;
      int m = end - e0; m = m < 64 ? m : 64;
      int k = 0;
      for (; k + 3 < m; k += 4) {
        int s0 = __shfl(idx, k, 64);
        int s1 = __shfl(idx, k + 1, 64);
        int s2 = __shfl(idx, k + 2, 64);
        int s3 = __shfl(idx, k + 3, 64);
        float v0 = h2f(H[(size_t)s0 * F_HID + lane]);
        float v1 = h2f(H[(size_t)s1 * F_HID + lane]);
        float v2 = h2f(H[(size_t)s2 * F_HID + lane]);
        float v3 = h2f(H[(size_t)s3 * F_HID + lane]);
        acc0 += v0 + v2;
        acc1 += v1 + v3;
      }
      for (; k < m; k++) {
        int s0 = __shfl(idx, k, 64);
        acc0 += h2f(H[(size_t)s0 * F_HID + lane]);
      }
    }
    float self = h2f(H[(size_t)n * F_HID + lane]);  // self-loop (already * dinv[n])
    float o = (acc0 + acc1 + self) * dinv[n] + bv;
    if (RELU) o = fmaxf(o, 0.f);
    OUT[(size_t)n * F_HID + lane] = f2h(o);
  }
}

// ---------------- PR GEMM (MFMA): PR[n][0:128]=O[n]@Wa ; [128:256]=O[n]@Wb, fp16 out ----
// Block handles output-column group g = blockIdx&3 (64 cols).
__global__ __launch_bounds__(256, 4) void k_gemm_pr(const unsigned short* __restrict__ O,
                                                    const void* __restrict__ fc1Wv,
                                                    unsigned short* __restrict__ PR, int N,
                                                    const int* __restrict__ flagp) {
  __shared__ unsigned short sWh[F_HID * 64];  // 8 KB fp16 slice, fragment order
  const bool isb = (*flagp != 0);
  const int g = blockIdx.x & 3;
  const int rowoff = (g & 2) ? 64 : 0;   // g>=2 -> Wb half (fc1W rows 64..127)
  const int coloff = (g & 1) * 64;
  int tid = threadIdx.x;
  for (int e = tid; e < F_HID * 64; e += 256) {
    int k = e >> 6, n = e & 63;
    int idx = (rowoff + k) * 128 + coloff + n;
    int c = k >> 5, q = (k >> 3) & 3, j = k & 7, t = n >> 4, m = n & 15;
    sWh[((c * 4 + t) * 64 + q * 16 + m) * 8 + j] =
        isb ? f2h(bf2f(((const unsigned short*)fc1Wv)[idx]))
            : f2h(((const float*)fc1Wv)[idx]);
  }
  __syncthreads();
  const int lane = tid & 63, wave = tid >> 6;
  const int m = lane & 15, q = lane >> 4;
  half8 bfrag[2][4];
#pragma unroll
  for (int c = 0; c < 2; c++)
#pragma unroll
    for (int t = 0; t < 4; t++)
      bfrag[c][t] = *reinterpret_cast<const half8*>(sWh + ((c * 4 + t) * 64 + lane) * 8);
  int ntiles = (N + 15) >> 4;
  int tstride = (gridDim.x >> 2) * 4;
  for (int tile = (blockIdx.x >> 2) * 4 + wave; tile < ntiles; tile += tstride) {
    int r0 = tile << 4;
    int rm = r0 + m; rm = rm < N ? rm : N - 1;
    floatx4 acc[4] = {{0.f,0.f,0.f,0.f},{0.f,0.f,0.f,0.f},{0.f,0.f,0.f,0.f},{0.f,0.f,0.f,0.f}};
#pragma unroll
    for (int c = 0; c < 2; c++) {
      half8 a = *reinterpret_cast<const half8*>(O + (size_t)rm * F_HID + c * 32 + q * 8);
#pragma unroll
      for (int t = 0; t < 4; t++)
        acc[t] = __builtin_amdgcn_mfma_f32_16x16x32_f16(a, bfrag[c][t], acc[t], 0, 0, 0);
    }
#pragma unroll
    for (int rr = 0; rr < 4; rr++) {
      int grow = r0 + q * 4 + rr;
      if (grow < N) {
#pragma unroll
        for (int t = 0; t < 4; t++)
          PR[(size_t)grow * 256 + g * 64 + t * 16 + m] = f2h(acc[t][rr]);
      }
    }
  }
}

// ---------------- query: out[q] = relu(P[i[q]] + R[j[q]] + fc1_b) @ fc2_W + fc2_b ----------------
__global__ __launch_bounds__(256) void k_query(const unsigned short* __restrict__ PRu,
                                               const int* __restrict__ qi,
                                               const int* __restrict__ qj,
                                               const void* __restrict__ fc1b,
                                               const void* __restrict__ fc2W,
                                               const void* __restrict__ fc2b,
                                               void* __restrict__ out, int Q,
                                               const int* __restrict__ flagp) {
  const bool isb = (*flagp != 0);
  int tid = threadIdx.x;
  int lane = tid & 63;
  int wave = tid >> 6;
  int g = lane >> 4, m = lane & 15;
  float bb[8], w0[8], w1[8];
#pragma unroll
  for (int t = 0; t < 8; t++) {
    int h = m * 8 + t;
    if (isb) {
      bb[t] = bf2f(((const unsigned short*)fc1b)[h]);
      w0[t] = bf2f(((const unsigned short*)fc2W)[h * 2 + 0]);
      w1[t] = bf2f(((const unsigned short*)fc2W)[h * 2 + 1]);
    } else {
      bb[t] = ((const float*)fc1b)[h];
      w0[t] = ((const float*)fc2W)[h * 2 + 0];
      w1[t] = ((const float*)fc2W)[h * 2 + 1];
    }
  }
  float ob0 = isb ? bf2f(((const unsigned short*)fc2b)[0]) : ((const float*)fc2b)[0];
  float ob1 = isb ? bf2f(((const unsigned short*)fc2b)[1]) : ((const float*)fc2b)[1];
  int gw = blockIdx.x * 4 + wave;
  int nW = gridDim.x * 4;
  int nQuad = (Q + 3) >> 2;
  for (int quad = gw; quad < nQuad; quad += nW) {
    int q = quad * 4 + g;
    int qq = q < Q ? q : Q - 1;
    int iq = qi[qq], jq = qj[qq];
    const ushort4* Pr = reinterpret_cast<const ushort4*>(PRu + (size_t)iq * 256) + m * 2;
    const ushort4* Rr = reinterpret_cast<const ushort4*>(PRu + (size_t)jq * 256 + 128) + m * 2;
    ushort4 pa = Pr[0], pb = Pr[1];
    ushort4 ra = Rr[0], rb = Rr[1];
    float h[8] = {h2f(pa.x) + h2f(ra.x), h2f(pa.y) + h2f(ra.y),
                  h2f(pa.z) + h2f(ra.z), h2f(pa.w) + h2f(ra.w),
                  h2f(pb.x) + h2f(rb.x), h2f(pb.y) + h2f(rb.y),
                  h2f(pb.z) + h2f(rb.z), h2f(pb.w) + h2f(rb.w)};
    float r0 = 0.f, r1 = 0.f;
#pragma unroll
    for (int t = 0; t < 8; t++) {
      float hv = fmaxf(h[t] + bb[t], 0.f);
      r0 += hv * w0[t];
      r1 += hv * w1[t];
    }
#pragma unroll
    for (int off = 8; off > 0; off >>= 1) {
      r0 += __shfl_xor(r0, off, 16);
      r1 += __shfl_xor(r1, off, 16);
    }
    if (m == 0 && q < Q) {
      if (isb) {
        *reinterpret_cast<ushort2*>((unsigned short*)out + (size_t)q * 2) =
            make_ushort2(f2bf(r0 + ob0), f2bf(r1 + ob1));
      } else {
        *reinterpret_cast<float2*>((float*)out + (size_t)q * 2) =
            make_float2(r0 + ob0, r1 + ob1);
      }
    }
  }
}

extern "C" void kernel_launch(void* const* d_in, const int* in_sizes, int n_in,
                              void* d_out, int out_size, void* d_ws, size_t ws_size,
                              hipStream_t stream) {
  const void* X    = d_in[0];
  const int*  edges= (const int*)d_in[1];
  const int*  qi   = (const int*)d_in[2];
  const int*  qj   = (const int*)d_in[3];
  const void* W1   = d_in[4];
  const void* b1   = d_in[5];
  const void* W2   = d_in[6];
  const void* b2   = d_in[7];
  const void* fc1W = d_in[8];
  const void* fc1b = d_in[9];
  const void* fc2W = d_in[10];
  const void* fc2b = d_in[11];

  const int N = in_sizes[0] / F_IN;
  const int E = in_sizes[1] / 2;
  const int Q = in_sizes[2];
  const int B = (N + NB - 1) / NB;           // buckets (<= MAXB for N <= 131072)
  const int chunk = (E + NWG - 1) / NWG;

  char* ws = (char*)d_ws;
  size_t off = 0;
  auto alloc = [&](size_t bytes) -> void* {
    void* p = ws + off;
    off += (bytes + 255) & ~(size_t)255;
    return p;
  };
  int*            flag = (int*)alloc(4);
  float*          dinv = (float*)alloc((size_t)N * 4);
  unsigned short* G    = (unsigned short*)alloc((size_t)N * F_HID * 2);  // gemm out (fp16)
  unsigned short* O    = (unsigned short*)alloc((size_t)N * F_HID * 2);  // layer out (fp16)
  unsigned short* PR   = (unsigned short*)alloc((size_t)N * 256 * 2);    // [P | R] fp16
  // bucket/CSR scratch aliases PR (all reads precede gemm_pr's PR writes)
  char* scr = (char*)PR;
  size_t soff = 0;
  auto salloc = [&](size_t bytes) -> void* {
    void* p = scr + soff;
    soff += (bytes + 255) & ~(size_t)255;
    return p;
  };
  int* hist = (int*)salloc((size_t)NWG * B * 4);
  int* btot = (int*)salloc((size_t)(B + 1) * 4);
  int* boff = (int*)salloc((size_t)(B + 1) * 4);
  int* buck = (int*)salloc((size_t)E * 4);
  int* csr  = (int*)salloc((size_t)E * 4);
  int* noff = (int*)salloc((size_t)(N + 1) * 4);
  (void)ws_size; (void)n_in; (void)out_size;

  const int* esrc = edges;
  const int* edst = edges + E;

  k_detect<<<1, 64, 0, stream>>>((const unsigned int*)X, flag);

  // bucket build + per-bucket counting sort -> exact CSR + noff + dinv
  k_bhist<<<NWG, 256, 0, stream>>>(edst, hist, E, B, chunk);
  k_bscan1<<<(B + 255) / 256, 256, 0, stream>>>(hist, btot, B);
  k_bscan2<<<1, 256, 0, stream>>>(btot, boff, B, E);
  k_bfill<<<NWG, 256, 0, stream>>>(esrc, edst, hist, boff, buck, E, B, chunk);
  k_bsort<<<B, 256, 0, stream>>>(buck, boff, csr, noff, dinv, N);

  // layer 1
  k_gemm1<<<2048, 256, 0, stream>>>(X, W1, dinv, G, N, flag);
  k_agg<true><<<2048, 256, 0, stream>>>(csr, noff, G, dinv, b1, O, N, flag);

  // layer 2
  k_gemm2<<<2048, 256, 0, stream>>>(O, W2, dinv, G, N, flag);
  k_agg<false><<<2048, 256, 0, stream>>>(csr, noff, G, dinv, b2, O, N, flag);

  // MLP factorization: PR = out2 @ [Wa | Wb]  (overwrites bucket scratch — safe)
  k_gemm_pr<<<2048, 256, 0, stream>>>(O, fc1W, PR, N, flag);

  // per-query: gather P[i] + R[j], relu, fc2
  k_query<<<4096, 256, 0, stream>>>(PR, qi, qj, fc1b, fc2W, fc2b, d_out, Q, flag);
}